// Round 1
// baseline (922.676 us; speedup 1.0000x reference)
//
#include <hip/hip_runtime.h>
#include <hip/hip_bf16.h>
#include <cstdint>

#define N_NODES 50000
#define N_EDGES 800000
#define NPAIRS  100000

// ---------------- graph preprocessing ----------------

__global__ __launch_bounds__(256) void deg_count_k(const int* __restrict__ ei, int* __restrict__ deg, int E) {
  int e = blockIdx.x * 256 + threadIdx.x;
  if (e < E) atomicAdd(&deg[ei[E + e]], 1);
}

__global__ __launch_bounds__(256) void dinv_k(const int* __restrict__ deg, float* __restrict__ dinv, int n) {
  int i = blockIdx.x * 256 + threadIdx.x;
  if (i < n) dinv[i] = rsqrtf((float)deg[i] + 1.0f);
}

// single-block exclusive scan over N degrees (wave shfl scan + serial wave-sum scan)
__global__ __launch_bounds__(1024) void scan_k(const int* __restrict__ deg, int* __restrict__ offs, int n) {
  __shared__ int wsum[16];
  __shared__ int wpre[16];
  __shared__ int run_s;
  int tid = threadIdx.x, lane = tid & 63, wid = tid >> 6;
  if (tid == 0) run_s = 0;
  __syncthreads();
  for (int base = 0; base < n; base += 1024) {
    int i = base + tid;
    int v = (i < n) ? deg[i] : 0;
    int s = v;
#pragma unroll
    for (int d = 1; d < 64; d <<= 1) {
      int t = __shfl_up(s, d);
      if (lane >= d) s += t;
    }
    if (lane == 63) wsum[wid] = s;
    __syncthreads();
    if (tid == 0) {
      int acc = run_s;
#pragma unroll
      for (int w = 0; w < 16; w++) { wpre[w] = acc; acc += wsum[w]; }
      run_s = acc;
    }
    __syncthreads();
    if (i < n) offs[i] = wpre[wid] + (s - v);
    __syncthreads();
  }
  if (tid == 0) offs[n] = run_s;
}

__global__ __launch_bounds__(256) void fill_k(const int* __restrict__ ei, const int* __restrict__ offs,
                                              int* __restrict__ cursor, int* __restrict__ csr, int E) {
  int e = blockIdx.x * 256 + threadIdx.x;
  if (e < E) {
    int s = ei[e], d = ei[E + e];
    int p = atomicAdd(&cursor[d], 1);
    csr[offs[d] + p] = s;
  }
}

// ---------------- dense layers ----------------

// out[n,128] = A[n,128] @ W[128,128]; 8 rows per block
__global__ __launch_bounds__(256) void gemm128_k(const float* __restrict__ A, const float* __restrict__ W,
                                                 float* __restrict__ out, int n) {
  __shared__ float xs[8 * 128];
  int tid = threadIdx.x;
  size_t row0 = (size_t)blockIdx.x * 8;
  *(float4*)&xs[tid * 4] = *(const float4*)&A[row0 * 128 + tid * 4];
  __syncthreads();
  int rl = tid >> 5;
  int c0 = (tid & 31) * 4;
  float4 acc = make_float4(0.f, 0.f, 0.f, 0.f);
  for (int k0 = 0; k0 < 128; k0 += 4) {
    float a[4];
    *(float4*)a = *(const float4*)&xs[rl * 128 + k0];
#pragma unroll
    for (int kk = 0; kk < 4; kk++) {
      float4 w = *(const float4*)&W[(k0 + kk) * 128 + c0];
      acc.x += a[kk] * w.x; acc.y += a[kk] * w.y;
      acc.z += a[kk] * w.z; acc.w += a[kk] * w.w;
    }
  }
  *(float4*)&out[(row0 + rl) * 128 + c0] = acc;
}

// CSR gather aggregation: one wave per node (64 lanes x float2 = 128 feats)
__global__ __launch_bounds__(256) void agg_k(const float* __restrict__ h, const float* __restrict__ dinv,
                                             const int* __restrict__ offs, const int* __restrict__ csr,
                                             const float* __restrict__ bias, float* __restrict__ out, int n) {
  int node = blockIdx.x * 4 + (threadIdx.x >> 6);
  if (node >= n) return;
  int lane = threadIdx.x & 63;
  float di = dinv[node];
  int e0 = offs[node], e1 = offs[node + 1];
  float ax = 0.f, ay = 0.f;
  for (int e = e0; e < e1; e++) {
    int s = csr[e];
    float c = dinv[s] * di;
    float2 v = *(const float2*)&h[(size_t)s * 128 + lane * 2];
    ax += c * v.x; ay += c * v.y;
  }
  float2 hv = *(const float2*)&h[(size_t)node * 128 + lane * 2];
  float sc = di * di;
  ax += sc * hv.x + bias[lane * 2];
  ay += sc * hv.y + bias[lane * 2 + 1];
  float2 r; r.x = ax; r.y = ay;
  *(float2*)&out[(size_t)node * 128 + lane * 2] = r;
}

// ---------------- batchnorm ----------------

__global__ __launch_bounds__(256) void bn_stats_k(const float* __restrict__ h, float* __restrict__ sums, int n) {
  __shared__ float red[512];
  int tid = threadIdx.x;
  int c = tid & 127, half = tid >> 7;
  float s = 0.f, s2 = 0.f;
  for (int r = blockIdx.x * 2 + half; r < n; r += gridDim.x * 2) {
    float v = h[(size_t)r * 128 + c];
    s += v; s2 += v * v;
  }
  red[tid] = s; red[256 + tid] = s2;
  __syncthreads();
  if (half == 0) {
    s  = red[tid] + red[tid + 128];
    s2 = red[256 + tid] + red[256 + tid + 128];
    atomicAdd(&sums[c], s);
    atomicAdd(&sums[128 + c], s2);
  }
}

__global__ __launch_bounds__(128) void bn_fin_k(const float* __restrict__ sums, const float* __restrict__ gamma,
                                                const float* __restrict__ beta, float* __restrict__ scsh) {
  int c = threadIdx.x;
  const float inv_n = 1.0f / (float)N_NODES;
  float mean = sums[c] * inv_n;
  float var = sums[128 + c] * inv_n - mean * mean;
  float sc = gamma[c] * rsqrtf(var + 1e-5f);
  scsh[c] = sc;
  scsh[128 + c] = beta[c] - mean * sc;
}

// in-place BN-apply + ReLU, float4 per thread
__global__ __launch_bounds__(256) void bn_apply_k(float* __restrict__ h, const float* __restrict__ scsh) {
  int idx = blockIdx.x * 256 + threadIdx.x;
  int c0 = (idx & 31) * 4;
  float4 v = *(float4*)&h[(size_t)idx * 4];
  float4 r;
  r.x = fmaxf(v.x * scsh[c0 + 0] + scsh[128 + c0 + 0], 0.f);
  r.y = fmaxf(v.y * scsh[c0 + 1] + scsh[128 + c0 + 1], 0.f);
  r.z = fmaxf(v.z * scsh[c0 + 2] + scsh[128 + c0 + 2], 0.f);
  r.w = fmaxf(v.w * scsh[c0 + 3] + scsh[128 + c0 + 3], 0.f);
  *(float4*)&h[(size_t)idx * 4] = r;
}

// ---------------- fused pair classifier ----------------
// 32 pairs per block; comb/z1/z2 staged in LDS; weights from L1/L2.

__global__ __launch_bounds__(256) void classifier_k(const float* __restrict__ h, const int* __restrict__ pairs,
    const float* __restrict__ Wc1, const float* __restrict__ bc1,
    const float* __restrict__ Wc2, const float* __restrict__ bc2,
    const float* __restrict__ Wc3, const float* __restrict__ bc3,
    float* __restrict__ out) {
  __shared__ float comb[32 * 260];
  __shared__ float z1s[32 * 132];
  __shared__ float z2s[32 * 68];
  __shared__ int nodes[64];
  int tid = threadIdx.x;
  int p0 = blockIdx.x * 32;
  if (tid < 64) nodes[tid] = pairs[p0 * 2 + tid];
  __syncthreads();
  int wave = tid >> 6, lane = tid & 63;
  for (int s = wave; s < 64; s += 4) {
    int nd = nodes[s];
    float2 v = *(const float2*)&h[(size_t)nd * 128 + lane * 2];
    int r = s >> 1;
    int base = r * 260 + (s & 1) * 128 + lane * 2;
    comb[base] = v.x; comb[base + 1] = v.y;
  }
  __syncthreads();
  int rg = tid >> 5;   // 0..7 (4 rows each)
  int cg = tid & 31;   // 0..31

  // phase 1: z1 = relu(comb @ Wc1 + bc1)   [32,256]@[256,128]
  {
    float acc[4][4];
#pragma unroll
    for (int j = 0; j < 4; j++) {
      float b = bc1[cg * 4 + j];
#pragma unroll
      for (int i = 0; i < 4; i++) acc[i][j] = b;
    }
    for (int k0 = 0; k0 < 256; k0 += 4) {
      float a[4][4];
#pragma unroll
      for (int i = 0; i < 4; i++)
        *(float4*)&a[i][0] = *(const float4*)&comb[(rg * 4 + i) * 260 + k0];
#pragma unroll
      for (int kk = 0; kk < 4; kk++) {
        float4 w = *(const float4*)&Wc1[(k0 + kk) * 128 + cg * 4];
#pragma unroll
        for (int i = 0; i < 4; i++) {
          acc[i][0] += a[i][kk] * w.x;
          acc[i][1] += a[i][kk] * w.y;
          acc[i][2] += a[i][kk] * w.z;
          acc[i][3] += a[i][kk] * w.w;
        }
      }
    }
#pragma unroll
    for (int i = 0; i < 4; i++) {
      float4 r4;
      r4.x = fmaxf(acc[i][0], 0.f); r4.y = fmaxf(acc[i][1], 0.f);
      r4.z = fmaxf(acc[i][2], 0.f); r4.w = fmaxf(acc[i][3], 0.f);
      *(float4*)&z1s[(rg * 4 + i) * 132 + cg * 4] = r4;
    }
  }
  __syncthreads();

  // phase 2: z2 = relu(z1 @ Wc2 + bc2)   [32,128]@[128,64]
  {
    float acc[4][2];
#pragma unroll
    for (int j = 0; j < 2; j++) {
      float b = bc2[cg * 2 + j];
#pragma unroll
      for (int i = 0; i < 4; i++) acc[i][j] = b;
    }
    for (int k0 = 0; k0 < 128; k0 += 4) {
      float a[4][4];
#pragma unroll
      for (int i = 0; i < 4; i++)
        *(float4*)&a[i][0] = *(const float4*)&z1s[(rg * 4 + i) * 132 + k0];
#pragma unroll
      for (int kk = 0; kk < 4; kk++) {
        float2 w = *(const float2*)&Wc2[(k0 + kk) * 64 + cg * 2];
#pragma unroll
        for (int i = 0; i < 4; i++) {
          acc[i][0] += a[i][kk] * w.x;
          acc[i][1] += a[i][kk] * w.y;
        }
      }
    }
#pragma unroll
    for (int i = 0; i < 4; i++) {
      float2 r2;
      r2.x = fmaxf(acc[i][0], 0.f); r2.y = fmaxf(acc[i][1], 0.f);
      *(float2*)&z2s[(rg * 4 + i) * 68 + cg * 2] = r2;
    }
  }
  __syncthreads();

  // phase 3: out = z2 @ Wc3 + bc3   [32,64]@[64,86]
  for (int o = tid; o < 32 * 86; o += 256) {
    int r = o / 86, c = o - r * 86;
    float acc = bc3[c];
#pragma unroll
    for (int k0 = 0; k0 < 64; k0 += 4) {
      float4 a = *(const float4*)&z2s[r * 68 + k0];
      acc += a.x * Wc3[(k0 + 0) * 86 + c];
      acc += a.y * Wc3[(k0 + 1) * 86 + c];
      acc += a.z * Wc3[(k0 + 2) * 86 + c];
      acc += a.w * Wc3[(k0 + 3) * 86 + c];
    }
    out[(size_t)(p0 + r) * 86 + c] = acc;
  }
}

// ---------------- launch ----------------

extern "C" void kernel_launch(void* const* d_in, const int* in_sizes, int n_in,
                              void* d_out, int out_size, void* d_ws, size_t ws_size,
                              hipStream_t stream) {
  (void)in_sizes; (void)n_in; (void)out_size; (void)ws_size;
  const float* x   = (const float*)d_in[0];
  const int*   ei  = (const int*)d_in[1];
  const int* pairs = (const int*)d_in[2];
  const float* W1  = (const float*)d_in[3];
  const float* b1  = (const float*)d_in[4];
  const float* g1  = (const float*)d_in[5];
  const float* be1 = (const float*)d_in[6];
  const float* W2  = (const float*)d_in[7];
  const float* b2  = (const float*)d_in[8];
  const float* g2  = (const float*)d_in[9];
  const float* be2 = (const float*)d_in[10];
  const float* Wc1 = (const float*)d_in[11];
  const float* bc1 = (const float*)d_in[12];
  const float* Wc2 = (const float*)d_in[13];
  const float* bc2 = (const float*)d_in[14];
  const float* Wc3 = (const float*)d_in[15];
  const float* bc3 = (const float*)d_in[16];
  float* out = (float*)d_out;

  size_t off = 0;
  auto alloc = [&](size_t bytes) -> char* {
    char* p = (char*)d_ws + off;
    off += (bytes + 255) & ~(size_t)255;
    return p;
  };
  int* deg      = (int*)alloc(N_NODES * 4);
  int* cursor   = (int*)alloc(N_NODES * 4);
  float* sums1  = (float*)alloc(256 * 4);
  float* sums2  = (float*)alloc(256 * 4);
  size_t zero_span = off;
  int* offs     = (int*)alloc((N_NODES + 1) * 4);
  int* csr      = (int*)alloc(N_EDGES * 4);
  float* dinv   = (float*)alloc(N_NODES * 4);
  float* scsh1  = (float*)alloc(256 * 4);
  float* scsh2  = (float*)alloc(256 * 4);
  float* bufA   = (float*)alloc((size_t)N_NODES * 128 * 4);
  float* bufB   = (float*)alloc((size_t)N_NODES * 128 * 4);

  hipMemsetAsync(d_ws, 0, zero_span, stream);
  deg_count_k<<<(N_EDGES + 255) / 256, 256, 0, stream>>>(ei, deg, N_EDGES);
  dinv_k<<<(N_NODES + 255) / 256, 256, 0, stream>>>(deg, dinv, N_NODES);
  scan_k<<<1, 1024, 0, stream>>>(deg, offs, N_NODES);
  fill_k<<<(N_EDGES + 255) / 256, 256, 0, stream>>>(ei, offs, cursor, csr, N_EDGES);

  // layer 1
  gemm128_k<<<N_NODES / 8, 256, 0, stream>>>(x, W1, bufA, N_NODES);
  agg_k<<<N_NODES / 4, 256, 0, stream>>>(bufA, dinv, offs, csr, b1, bufB, N_NODES);
  bn_stats_k<<<256, 256, 0, stream>>>(bufB, sums1, N_NODES);
  bn_fin_k<<<1, 128, 0, stream>>>(sums1, g1, be1, scsh1);
  bn_apply_k<<<N_NODES / 8, 256, 0, stream>>>(bufB, scsh1);

  // layer 2
  gemm128_k<<<N_NODES / 8, 256, 0, stream>>>(bufB, W2, bufA, N_NODES);
  agg_k<<<N_NODES / 4, 256, 0, stream>>>(bufA, dinv, offs, csr, b2, bufB, N_NODES);
  bn_stats_k<<<256, 256, 0, stream>>>(bufB, sums2, N_NODES);
  bn_fin_k<<<1, 128, 0, stream>>>(sums2, g2, be2, scsh2);
  bn_apply_k<<<N_NODES / 8, 256, 0, stream>>>(bufB, scsh2);

  // classifier
  classifier_k<<<NPAIRS / 32, 256, 0, stream>>>(bufB, pairs, Wc1, bc1, Wc2, bc2, Wc3, bc3, out);
}

// Round 3
// 508.623 us; speedup vs baseline: 1.8141x; 1.8141x over previous
//
#include <hip/hip_runtime.h>
#include <cstdint>

#define N_NODES 50000
#define N_EDGES 800000
#define NPAIRS  100000

typedef unsigned short u16;
typedef short short8v __attribute__((ext_vector_type(8)));
typedef float f32x4 __attribute__((ext_vector_type(4)));

static __device__ __forceinline__ u16 f2bf(float f) {
  unsigned int u = __float_as_uint(f);
  u += 0x7FFF + ((u >> 16) & 1);
  return (u16)(u >> 16);
}

// ---------------- graph preprocessing ----------------

__global__ __launch_bounds__(256) void deg_count_k(const int* __restrict__ ei, int* __restrict__ deg, int E) {
  int e = blockIdx.x * 256 + threadIdx.x;
  if (e < E) atomicAdd(&deg[ei[E + e]], 1);
}

__global__ __launch_bounds__(256) void dinv_k(const int* __restrict__ deg, float* __restrict__ dinv, int n) {
  int i = blockIdx.x * 256 + threadIdx.x;
  if (i < n) dinv[i] = rsqrtf((float)deg[i] + 1.0f);
}

// single-block exclusive scan, 4 elements/thread
__global__ __launch_bounds__(1024) void scan_k(const int* __restrict__ deg, int* __restrict__ offs, int n) {
  __shared__ int wsum[16];
  __shared__ int wpre[16];
  __shared__ int run_s;
  int tid = threadIdx.x, lane = tid & 63, wid = tid >> 6;
  if (tid == 0) run_s = 0;
  __syncthreads();
  for (int base = 0; base < n; base += 4096) {
    int i4 = base + tid * 4;
    int4 v = make_int4(0, 0, 0, 0);
    if (i4 + 3 < n) v = *(const int4*)&deg[i4];
    else {
      if (i4 < n) v.x = deg[i4];
      if (i4 + 1 < n) v.y = deg[i4 + 1];
      if (i4 + 2 < n) v.z = deg[i4 + 2];
      if (i4 + 3 < n) v.w = deg[i4 + 3];
    }
    int tsum = v.x + v.y + v.z + v.w;
    int s = tsum;
#pragma unroll
    for (int d = 1; d < 64; d <<= 1) {
      int t = __shfl_up(s, d);
      if (lane >= d) s += t;
    }
    if (lane == 63) wsum[wid] = s;
    __syncthreads();
    if (tid == 0) {
      int acc = run_s;
#pragma unroll
      for (int w = 0; w < 16; w++) { wpre[w] = acc; acc += wsum[w]; }
      run_s = acc;
    }
    __syncthreads();
    int pre = wpre[wid] + (s - tsum);
    int4 o;
    o.x = pre; o.y = pre + v.x; o.z = o.y + v.y; o.w = o.z + v.z;
    if (i4 + 3 < n) *(int4*)&offs[i4] = o;
    else {
      if (i4 < n) offs[i4] = o.x;
      if (i4 + 1 < n) offs[i4 + 1] = o.y;
      if (i4 + 2 < n) offs[i4 + 2] = o.z;
      if (i4 + 3 < n) offs[i4 + 3] = o.w;
    }
    __syncthreads();
  }
  if (tid == 0) offs[n] = run_s;
}

__global__ __launch_bounds__(256) void fill_k(const int* __restrict__ ei, const int* __restrict__ offs,
                                              int* __restrict__ cursor, int* __restrict__ csr,
                                              float* __restrict__ csrc, const float* __restrict__ dinv, int E) {
  int e = blockIdx.x * 256 + threadIdx.x;
  if (e < E) {
    int s = ei[e], d = ei[E + e];
    int p = atomicAdd(&cursor[d], 1);
    int idx = offs[d] + p;
    csr[idx] = s;
    csrc[idx] = dinv[s];
  }
}

// pack classifier weights into frag-linear bf16 layouts
__global__ __launch_bounds__(256) void prep_w_k(const float* __restrict__ Wc1, const float* __restrict__ Wc2,
                                                const float* __restrict__ Wc3,
                                                u16* __restrict__ Wc1F, u16* __restrict__ Wc2F, u16* __restrict__ Wc3F) {
  int slot = blockIdx.x * 256 + threadIdx.x;
  if (slot < 4096) {           // Wc1: K=256, N=128 -> nt 0..7, ks 0..7
    int lane = slot & 63, j = lane & 15, kg = lane >> 4;
    int ks = (slot >> 6) & 7, nt = slot >> 9;
    int k0 = ks * 32 + kg * 8, c = nt * 16 + j;
#pragma unroll
    for (int e = 0; e < 8; e++) Wc1F[(size_t)slot * 8 + e] = f2bf(Wc1[(k0 + e) * 128 + c]);
  } else if (slot < 5120) {    // Wc2: K=128, N=64 -> nt 0..3, ks 0..3
    int s2 = slot - 4096;
    int lane = s2 & 63, j = lane & 15, kg = lane >> 4;
    int ks = (s2 >> 6) & 3, nt = s2 >> 8;
    int k0 = ks * 32 + kg * 8, c = nt * 16 + j;
#pragma unroll
    for (int e = 0; e < 8; e++) Wc2F[(size_t)s2 * 8 + e] = f2bf(Wc2[(k0 + e) * 64 + c]);
  } else if (slot < 6144) {    // Wc3: K=64, N=86 padded to 128 -> nt 0..7, ks 0..1
    int s3 = slot - 5120;
    int lane = s3 & 63, j = lane & 15, kg = lane >> 4;
    int ks = (s3 >> 6) & 1, nt = s3 >> 7;
    int k0 = ks * 32 + kg * 8, c = nt * 16 + j;
#pragma unroll
    for (int e = 0; e < 8; e++)
      Wc3F[(size_t)s3 * 8 + e] = f2bf((c < 86) ? Wc3[(k0 + e) * 86 + c] : 0.f);
  }
}

// ---------------- dense layers ----------------

// out[n,128] = A[n,128] @ W[128,128]; 32 rows/block, 4x4 microtile
__global__ __launch_bounds__(256) void gemm32_k(const float* __restrict__ A, const float* __restrict__ W,
                                                float* __restrict__ out, int n) {
  __shared__ float As[32 * 132];
  int tid = threadIdx.x;
  int row0 = blockIdx.x * 32;
#pragma unroll
  for (int i = 0; i < 4; i++) {
    int r = i * 8 + (tid >> 5);
    int c = (tid & 31) * 4;
    int gr = row0 + r; if (gr >= n) gr = n - 1;
    *(float4*)&As[r * 132 + c] = *(const float4*)&A[(size_t)gr * 128 + c];
  }
  __syncthreads();
  int tr = (tid >> 5) * 4;
  int tc = (tid & 31) * 4;
  float acc[4][4];
#pragma unroll
  for (int i = 0; i < 4; i++)
#pragma unroll
    for (int j = 0; j < 4; j++) acc[i][j] = 0.f;
  for (int k0 = 0; k0 < 128; k0 += 4) {
    float a[4][4];
#pragma unroll
    for (int i = 0; i < 4; i++)
      *(float4*)&a[i][0] = *(const float4*)&As[(tr + i) * 132 + k0];
#pragma unroll
    for (int kk = 0; kk < 4; kk++) {
      float4 w = *(const float4*)&W[(k0 + kk) * 128 + tc];
#pragma unroll
      for (int i = 0; i < 4; i++) {
        acc[i][0] += a[i][kk] * w.x;
        acc[i][1] += a[i][kk] * w.y;
        acc[i][2] += a[i][kk] * w.z;
        acc[i][3] += a[i][kk] * w.w;
      }
    }
  }
#pragma unroll
  for (int i = 0; i < 4; i++) {
    int gr = row0 + tr + i;
    if (gr < n) *(float4*)&out[(size_t)gr * 128 + tc] = *(float4*)&acc[i][0];
  }
}

// CSR gather aggregation: one wave/node, streamed dinv[src], 4x unroll
__global__ __launch_bounds__(256) void agg_k(const float* __restrict__ h, const float* __restrict__ dinv,
                                             const int* __restrict__ offs, const int* __restrict__ csr,
                                             const float* __restrict__ csrc,
                                             const float* __restrict__ bias, float* __restrict__ out, int n) {
  int node = blockIdx.x * 4 + (threadIdx.x >> 6);
  if (node >= n) return;
  int lane = threadIdx.x & 63;
  float di = dinv[node];
  int e0 = offs[node], e1 = offs[node + 1];
  float a0x = 0.f, a0y = 0.f, a1x = 0.f, a1y = 0.f;
  float a2x = 0.f, a2y = 0.f, a3x = 0.f, a3y = 0.f;
  int e = e0;
  for (; e + 4 <= e1; e += 4) {
    int s0 = csr[e], s1 = csr[e + 1], s2 = csr[e + 2], s3 = csr[e + 3];
    float c0 = csrc[e], c1 = csrc[e + 1], c2 = csrc[e + 2], c3 = csrc[e + 3];
    float2 v0 = *(const float2*)&h[(size_t)s0 * 128 + lane * 2];
    float2 v1 = *(const float2*)&h[(size_t)s1 * 128 + lane * 2];
    float2 v2 = *(const float2*)&h[(size_t)s2 * 128 + lane * 2];
    float2 v3 = *(const float2*)&h[(size_t)s3 * 128 + lane * 2];
    a0x += c0 * v0.x; a0y += c0 * v0.y;
    a1x += c1 * v1.x; a1y += c1 * v1.y;
    a2x += c2 * v2.x; a2y += c2 * v2.y;
    a3x += c3 * v3.x; a3y += c3 * v3.y;
  }
  for (; e < e1; e++) {
    int s0 = csr[e];
    float c0 = csrc[e];
    float2 v0 = *(const float2*)&h[(size_t)s0 * 128 + lane * 2];
    a0x += c0 * v0.x; a0y += c0 * v0.y;
  }
  float sx = (a0x + a1x) + (a2x + a3x);
  float sy = (a0y + a1y) + (a2y + a3y);
  float2 hv = *(const float2*)&h[(size_t)node * 128 + lane * 2];
  float sc = di * di;
  float rx = di * sx + sc * hv.x + bias[lane * 2];
  float ry = di * sy + sc * hv.y + bias[lane * 2 + 1];
  float2 r; r.x = rx; r.y = ry;
  *(float2*)&out[(size_t)node * 128 + lane * 2] = r;
}

// ---------------- batchnorm ----------------

__global__ __launch_bounds__(256) void bn_stats_k(const float* __restrict__ h, float* __restrict__ sums, int n) {
  __shared__ float red[512];
  int tid = threadIdx.x;
  int c = tid & 127, half = tid >> 7;
  float s = 0.f, s2 = 0.f;
  for (int r = blockIdx.x * 2 + half; r < n; r += gridDim.x * 2) {
    float v = h[(size_t)r * 128 + c];
    s += v; s2 += v * v;
  }
  red[tid] = s; red[256 + tid] = s2;
  __syncthreads();
  if (half == 0) {
    s  = red[tid] + red[tid + 128];
    s2 = red[256 + tid] + red[256 + tid + 128];
    atomicAdd(&sums[c], s);
    atomicAdd(&sums[128 + c], s2);
  }
}

__global__ __launch_bounds__(128) void bn_fin_k(const float* __restrict__ sums, const float* __restrict__ gamma,
                                                const float* __restrict__ beta, float* __restrict__ scsh) {
  int c = threadIdx.x;
  const float inv_n = 1.0f / (float)N_NODES;
  float mean = sums[c] * inv_n;
  float var = sums[128 + c] * inv_n - mean * mean;
  float sc = gamma[c] * rsqrtf(var + 1e-5f);
  scsh[c] = sc;
  scsh[128 + c] = beta[c] - mean * sc;
}

__global__ __launch_bounds__(256) void bn_apply_k(float* __restrict__ h, const float* __restrict__ scsh) {
  int idx = blockIdx.x * 256 + threadIdx.x;
  int c0 = (idx & 31) * 4;
  float4 v = *(float4*)&h[(size_t)idx * 4];
  float4 r;
  r.x = fmaxf(v.x * scsh[c0 + 0] + scsh[128 + c0 + 0], 0.f);
  r.y = fmaxf(v.y * scsh[c0 + 1] + scsh[128 + c0 + 1], 0.f);
  r.z = fmaxf(v.z * scsh[c0 + 2] + scsh[128 + c0 + 2], 0.f);
  r.w = fmaxf(v.w * scsh[c0 + 3] + scsh[128 + c0 + 3], 0.f);
  *(float4*)&h[(size_t)idx * 4] = r;
}

// layer-2 BN+ReLU, emit bf16 (classifier input)
__global__ __launch_bounds__(256) void bn_apply_bf16_k(const float* __restrict__ h, const float* __restrict__ scsh,
                                                       u16* __restrict__ hb) {
  int idx = blockIdx.x * 256 + threadIdx.x;
  int c0 = (idx & 31) * 4;
  float4 v = *(const float4*)&h[(size_t)idx * 4];
  ushort4 o;
  o.x = f2bf(fmaxf(v.x * scsh[c0 + 0] + scsh[128 + c0 + 0], 0.f));
  o.y = f2bf(fmaxf(v.y * scsh[c0 + 1] + scsh[128 + c0 + 1], 0.f));
  o.z = f2bf(fmaxf(v.z * scsh[c0 + 2] + scsh[128 + c0 + 2], 0.f));
  o.w = f2bf(fmaxf(v.w * scsh[c0 + 3] + scsh[128 + c0 + 3], 0.f));
  *(ushort4*)&hb[(size_t)idx * 4] = o;
}

// ---------------- fused pair classifier (bf16 MFMA) ----------------
// 64 pairs/block, 4 waves. comb[64x256]bf16 (528B rows), z1[64x128]bf16 (272B),
// z2[64x64]bf16 (144B, aliases comb). Weights pre-packed frag-linear.

#define SM_Z1 33792
#define SM_TOT (33792 + 17408)

__global__ __launch_bounds__(256) void classifier_k(const u16* __restrict__ hbf, const int* __restrict__ pairs,
    const u16* __restrict__ Wc1F, const float* __restrict__ bc1,
    const u16* __restrict__ Wc2F, const float* __restrict__ bc2,
    const u16* __restrict__ Wc3F, const float* __restrict__ bc3,
    float* __restrict__ out) {
  __shared__ __align__(16) char smem[SM_TOT];
  __shared__ int nodes[128];
  int tid = threadIdx.x;
  int p0 = blockIdx.x * 64;
  if (tid < 128) {
    int gi = p0 * 2 + tid;
    nodes[tid] = (gi < NPAIRS * 2) ? pairs[gi] : 0;
  }
  __syncthreads();
  int w = tid >> 6, lane = tid & 63;
  int li = lane & 15, kg = lane >> 4;

  // gather 128 node halves -> comb (row-major bf16, 528B pair stride)
  {
    unsigned int* cmb = (unsigned int*)smem;
    for (int s = w * 32; s < w * 32 + 32; s++) {
      int nd = nodes[s];
      unsigned int v = ((const unsigned int*)hbf)[(size_t)nd * 64 + lane];
      cmb[(s >> 1) * 132 + (s & 1) * 64 + lane] = v;
    }
  }
  __syncthreads();

  // phase 1: z1 = relu(comb @ Wc1 + bc1)   M=64 K=256 N=128; wave -> N-tiles {2w,2w+1}
  {
    f32x4 acc[4][2];
#pragma unroll
    for (int ntl = 0; ntl < 2; ntl++) {
      float b = bc1[(2 * w + ntl) * 16 + li];
#pragma unroll
      for (int mt = 0; mt < 4; mt++)
#pragma unroll
        for (int q = 0; q < 4; q++) acc[mt][ntl][q] = b;
    }
    for (int ks = 0; ks < 8; ks++) {
      short8v a[4];
#pragma unroll
      for (int mt = 0; mt < 4; mt++)
        a[mt] = *(const short8v*)(smem + (mt * 16 + li) * 528 + kg * 16 + ks * 64);
#pragma unroll
      for (int ntl = 0; ntl < 2; ntl++) {
        int nt = 2 * w + ntl;
        short8v b = *(const short8v*)(Wc1F + ((size_t)(nt * 8 + ks) * 64 + lane) * 8);
#pragma unroll
        for (int mt = 0; mt < 4; mt++)
          acc[mt][ntl] = __builtin_amdgcn_mfma_f32_16x16x32_bf16(a[mt], b, acc[mt][ntl], 0, 0, 0);
      }
    }
#pragma unroll
    for (int mt = 0; mt < 4; mt++)
#pragma unroll
      for (int ntl = 0; ntl < 2; ntl++)
#pragma unroll
        for (int r = 0; r < 4; r++) {
          int row = mt * 16 + kg * 4 + r;
          int col = (2 * w + ntl) * 16 + li;
          *(u16*)(smem + SM_Z1 + row * 272 + col * 2) = f2bf(fmaxf(acc[mt][ntl][r], 0.f));
        }
  }
  __syncthreads();

  // phase 2: z2 = relu(z1 @ Wc2 + bc2)   M=64 K=128 N=64; wave -> N-tile w
  {
    f32x4 acc[4];
    float b = bc2[w * 16 + li];
#pragma unroll
    for (int mt = 0; mt < 4; mt++)
#pragma unroll
      for (int q = 0; q < 4; q++) acc[mt][q] = b;
    for (int ks = 0; ks < 4; ks++) {
      short8v a[4];
#pragma unroll
      for (int mt = 0; mt < 4; mt++)
        a[mt] = *(const short8v*)(smem + SM_Z1 + (mt * 16 + li) * 272 + kg * 16 + ks * 64);
      short8v bf = *(const short8v*)(Wc2F + ((size_t)(w * 4 + ks) * 64 + lane) * 8);
#pragma unroll
      for (int mt = 0; mt < 4; mt++)
        acc[mt] = __builtin_amdgcn_mfma_f32_16x16x32_bf16(a[mt], bf, acc[mt], 0, 0, 0);
    }
#pragma unroll
    for (int mt = 0; mt < 4; mt++)
#pragma unroll
      for (int r = 0; r < 4; r++) {
        int row = mt * 16 + kg * 4 + r;
        int col = w * 16 + li;
        *(u16*)(smem + row * 144 + col * 2) = f2bf(fmaxf(acc[mt][r], 0.f));
      }
  }
  __syncthreads();

  // phase 3: out = z2 @ Wc3 + bc3   M=64 K=64 N=86 (padded 128); wave -> N-tiles {2w,2w+1}
  {
    f32x4 acc[4][2];
#pragma unroll
    for (int ntl = 0; ntl < 2; ntl++) {
      int col = (2 * w + ntl) * 16 + li;
      float b = (col < 86) ? bc3[col] : 0.f;
#pragma unroll
      for (int mt = 0; mt < 4; mt++)
#pragma unroll
        for (int q = 0; q < 4; q++) acc[mt][ntl][q] = b;
    }
    for (int ks = 0; ks < 2; ks++) {
      short8v a[4];
#pragma unroll
      for (int mt = 0; mt < 4; mt++)
        a[mt] = *(const short8v*)(smem + (mt * 16 + li) * 144 + kg * 16 + ks * 64);
#pragma unroll
      for (int ntl = 0; ntl < 2; ntl++) {
        int nt = 2 * w + ntl;
        short8v bf = *(const short8v*)(Wc3F + ((size_t)(nt * 2 + ks) * 64 + lane) * 8);
#pragma unroll
        for (int mt = 0; mt < 4; mt++)
          acc[mt][ntl] = __builtin_amdgcn_mfma_f32_16x16x32_bf16(a[mt], bf, acc[mt][ntl], 0, 0, 0);
      }
    }
#pragma unroll
    for (int mt = 0; mt < 4; mt++)
#pragma unroll
      for (int ntl = 0; ntl < 2; ntl++) {
        int col = (2 * w + ntl) * 16 + li;
        if (col < 86) {
#pragma unroll
          for (int r = 0; r < 4; r++) {
            int row = p0 + mt * 16 + kg * 4 + r;
            if (row < NPAIRS) out[(size_t)row * 86 + col] = acc[mt][ntl][r];
          }
        }
      }
  }
}

// ---------------- launch ----------------

extern "C" void kernel_launch(void* const* d_in, const int* in_sizes, int n_in,
                              void* d_out, int out_size, void* d_ws, size_t ws_size,
                              hipStream_t stream) {
  (void)in_sizes; (void)n_in; (void)out_size; (void)ws_size;
  const float* x   = (const float*)d_in[0];
  const int*   ei  = (const int*)d_in[1];
  const int* pairs = (const int*)d_in[2];
  const float* W1  = (const float*)d_in[3];
  const float* b1  = (const float*)d_in[4];
  const float* g1  = (const float*)d_in[5];
  const float* be1 = (const float*)d_in[6];
  const float* W2  = (const float*)d_in[7];
  const float* b2  = (const float*)d_in[8];
  const float* g2  = (const float*)d_in[9];
  const float* be2 = (const float*)d_in[10];
  const float* Wc1 = (const float*)d_in[11];
  const float* bc1 = (const float*)d_in[12];
  const float* Wc2 = (const float*)d_in[13];
  const float* bc2 = (const float*)d_in[14];
  const float* Wc3 = (const float*)d_in[15];
  const float* bc3 = (const float*)d_in[16];
  float* out = (float*)d_out;

  size_t off = 0;
  auto alloc = [&](size_t bytes) -> char* {
    char* p = (char*)d_ws + off;
    off += (bytes + 255) & ~(size_t)255;
    return p;
  };
  int* deg      = (int*)alloc(N_NODES * 4);
  int* cursor   = (int*)alloc(N_NODES * 4);
  float* sums1  = (float*)alloc(256 * 4);
  float* sums2  = (float*)alloc(256 * 4);
  size_t zero_span = off;
  int* offs     = (int*)alloc((N_NODES + 1) * 4);
  int* csr      = (int*)alloc(N_EDGES * 4);
  float* csrc   = (float*)alloc(N_EDGES * 4);
  float* dinv   = (float*)alloc(N_NODES * 4);
  float* scsh1  = (float*)alloc(256 * 4);
  float* scsh2  = (float*)alloc(256 * 4);
  u16* Wc1F     = (u16*)alloc(4096 * 8 * 2);
  u16* Wc2F     = (u16*)alloc(1024 * 8 * 2);
  u16* Wc3F     = (u16*)alloc(1024 * 8 * 2);
  float* bufA   = (float*)alloc((size_t)N_NODES * 128 * 4);
  float* bufB   = (float*)alloc((size_t)N_NODES * 128 * 4);
  u16* hbf      = (u16*)bufA;   // aliases bufA (dead after agg2)

  hipMemsetAsync(d_ws, 0, zero_span, stream);
  deg_count_k<<<(N_EDGES + 255) / 256, 256, 0, stream>>>(ei, deg, N_EDGES);
  dinv_k<<<(N_NODES + 255) / 256, 256, 0, stream>>>(deg, dinv, N_NODES);
  scan_k<<<1, 1024, 0, stream>>>(deg, offs, N_NODES);
  fill_k<<<(N_EDGES + 255) / 256, 256, 0, stream>>>(ei, offs, cursor, csr, csrc, dinv, N_EDGES);
  prep_w_k<<<24, 256, 0, stream>>>(Wc1, Wc2, Wc3, Wc1F, Wc2F, Wc3F);

  // layer 1
  gemm32_k<<<(N_NODES + 31) / 32, 256, 0, stream>>>(x, W1, bufA, N_NODES);
  agg_k<<<N_NODES / 4, 256, 0, stream>>>(bufA, dinv, offs, csr, csrc, b1, bufB, N_NODES);
  bn_stats_k<<<256, 256, 0, stream>>>(bufB, sums1, N_NODES);
  bn_fin_k<<<1, 128, 0, stream>>>(sums1, g1, be1, scsh1);
  bn_apply_k<<<N_NODES / 8, 256, 0, stream>>>(bufB, scsh1);

  // layer 2
  gemm32_k<<<(N_NODES + 31) / 32, 256, 0, stream>>>(bufB, W2, bufA, N_NODES);
  agg_k<<<N_NODES / 4, 256, 0, stream>>>(bufA, dinv, offs, csr, csrc, b2, bufB, N_NODES);
  bn_stats_k<<<256, 256, 0, stream>>>(bufB, sums2, N_NODES);
  bn_fin_k<<<1, 128, 0, stream>>>(sums2, g2, be2, scsh2);
  bn_apply_bf16_k<<<N_NODES / 8, 256, 0, stream>>>(bufB, scsh2, hbf);

  // classifier
  classifier_k<<<(NPAIRS + 63) / 64, 256, 0, stream>>>(hbf, pairs, Wc1F, bc1, Wc2F, bc2, Wc3F, bc3, out);
}

// Round 4
// 397.381 us; speedup vs baseline: 2.3219x; 1.2799x over previous
//
#include <hip/hip_runtime.h>
#include <cstdint>

#define N_NODES 50000
#define N_EDGES 800000
#define NPAIRS  100000

typedef unsigned short u16;
typedef unsigned int u32;
typedef _Float16 f16;
typedef short short8v __attribute__((ext_vector_type(8)));
typedef _Float16 h8 __attribute__((ext_vector_type(8)));
typedef _Float16 h4 __attribute__((ext_vector_type(4)));
typedef float f32x4 __attribute__((ext_vector_type(4)));

static __device__ __forceinline__ u16 f2bf(float f) {
  unsigned int u = __float_as_uint(f);
  u += 0x7FFF + ((u >> 16) & 1);
  return (u16)(u >> 16);
}

// ---------------- graph preprocessing ----------------

__global__ __launch_bounds__(256) void deg_count_k(const int* __restrict__ ei, int* __restrict__ deg, int E) {
  int e = blockIdx.x * 256 + threadIdx.x;
  if (e < E) atomicAdd(&deg[ei[E + e]], 1);
}

__global__ __launch_bounds__(256) void dinv_k(const int* __restrict__ deg, float* __restrict__ dinv, int n) {
  int i = blockIdx.x * 256 + threadIdx.x;
  if (i < n) dinv[i] = rsqrtf((float)deg[i] + 1.0f);
}

// single-block exclusive scan, 4 elements/thread
__global__ __launch_bounds__(1024) void scan_k(const int* __restrict__ deg, int* __restrict__ offs, int n) {
  __shared__ int wsum[16];
  __shared__ int wpre[16];
  __shared__ int run_s;
  int tid = threadIdx.x, lane = tid & 63, wid = tid >> 6;
  if (tid == 0) run_s = 0;
  __syncthreads();
  for (int base = 0; base < n; base += 4096) {
    int i4 = base + tid * 4;
    int4 v = make_int4(0, 0, 0, 0);
    if (i4 + 3 < n) v = *(const int4*)&deg[i4];
    else {
      if (i4 < n) v.x = deg[i4];
      if (i4 + 1 < n) v.y = deg[i4 + 1];
      if (i4 + 2 < n) v.z = deg[i4 + 2];
      if (i4 + 3 < n) v.w = deg[i4 + 3];
    }
    int tsum = v.x + v.y + v.z + v.w;
    int s = tsum;
#pragma unroll
    for (int d = 1; d < 64; d <<= 1) {
      int t = __shfl_up(s, d);
      if (lane >= d) s += t;
    }
    if (lane == 63) wsum[wid] = s;
    __syncthreads();
    if (tid == 0) {
      int acc = run_s;
#pragma unroll
      for (int w = 0; w < 16; w++) { wpre[w] = acc; acc += wsum[w]; }
      run_s = acc;
    }
    __syncthreads();
    int pre = wpre[wid] + (s - tsum);
    int4 o;
    o.x = pre; o.y = pre + v.x; o.z = o.y + v.y; o.w = o.z + v.z;
    if (i4 + 3 < n) *(int4*)&offs[i4] = o;
    else {
      if (i4 < n) offs[i4] = o.x;
      if (i4 + 1 < n) offs[i4 + 1] = o.y;
      if (i4 + 2 < n) offs[i4 + 2] = o.z;
      if (i4 + 3 < n) offs[i4 + 3] = o.w;
    }
    __syncthreads();
  }
  if (tid == 0) offs[n] = run_s;
}

__global__ __launch_bounds__(256) void fill_k(const int* __restrict__ ei, const int* __restrict__ offs,
                                              int* __restrict__ cursor, int* __restrict__ csr,
                                              float* __restrict__ csrc, const float* __restrict__ dinv, int E) {
  int e = blockIdx.x * 256 + threadIdx.x;
  if (e < E) {
    int s = ei[e], d = ei[E + e];
    int p = atomicAdd(&cursor[d], 1);
    int idx = offs[d] + p;
    csr[idx] = s;
    csrc[idx] = dinv[s];
  }
}

// pack weights: W1/W2 -> fp16 frag-linear; Wc1/Wc2/Wc3 -> bf16 frag-linear
__global__ __launch_bounds__(256) void prep_w_k(const float* __restrict__ W1, const float* __restrict__ W2,
                                                const float* __restrict__ Wc1, const float* __restrict__ Wc2,
                                                const float* __restrict__ Wc3,
                                                f16* __restrict__ W1F, f16* __restrict__ W2F,
                                                u16* __restrict__ Wc1F, u16* __restrict__ Wc2F, u16* __restrict__ Wc3F) {
  int slot = blockIdx.x * 256 + threadIdx.x;
  int lane = slot & 63, j = lane & 15, kg = lane >> 4;
  if (slot < 2048) {           // W1: K=128, N=128 (fp16)
    int ks = (slot >> 6) & 3, nt = slot >> 8;
    int k0 = ks * 32 + kg * 8, c = nt * 16 + j;
#pragma unroll
    for (int e = 0; e < 8; e++) W1F[(size_t)slot * 8 + e] = (f16)W1[(k0 + e) * 128 + c];
  } else if (slot < 4096) {    // W2: K=128, N=128 (fp16)
    int s2 = slot - 2048;
    int ks = (s2 >> 6) & 3, nt = s2 >> 8;
    int k0 = ks * 32 + kg * 8, c = nt * 16 + j;
#pragma unroll
    for (int e = 0; e < 8; e++) W2F[(size_t)s2 * 8 + e] = (f16)W2[(k0 + e) * 128 + c];
  } else if (slot < 8192) {    // Wc1: K=256, N=128 (bf16)
    int s3 = slot - 4096;
    int ks = (s3 >> 6) & 7, nt = s3 >> 9;
    int k0 = ks * 32 + kg * 8, c = nt * 16 + j;
#pragma unroll
    for (int e = 0; e < 8; e++) Wc1F[(size_t)s3 * 8 + e] = f2bf(Wc1[(k0 + e) * 128 + c]);
  } else if (slot < 9216) {    // Wc2: K=128, N=64 (bf16)
    int s4 = slot - 8192;
    int ks = (s4 >> 6) & 3, nt = s4 >> 8;
    int k0 = ks * 32 + kg * 8, c = nt * 16 + j;
#pragma unroll
    for (int e = 0; e < 8; e++) Wc2F[(size_t)s4 * 8 + e] = f2bf(Wc2[(k0 + e) * 64 + c]);
  } else if (slot < 10240) {   // Wc3: K=64, N=86 padded 128 (bf16)
    int s5 = slot - 9216;
    int ks = (s5 >> 6) & 1, nt = s5 >> 7;
    int k0 = ks * 32 + kg * 8, c = nt * 16 + j;
#pragma unroll
    for (int e = 0; e < 8; e++)
      Wc3F[(size_t)s5 * 8 + e] = f2bf((c < 86) ? Wc3[(k0 + e) * 86 + c] : 0.f);
  }
}

// ---------------- fp16 MFMA node GEMM ----------------
// out[n,128](fp16) = bnrelu?(A[n,128] fp32) @ W[128,128]; 64 rows/block, 4 waves.
// scsh != null: apply per-column scale/shift + ReLU during staging (fused BN).

__global__ __launch_bounds__(256) void gemm_mfma_k(const float* __restrict__ A,
                                                   const float* __restrict__ scsh,
                                                   const f16* __restrict__ WF,
                                                   f16* __restrict__ outh, int n) {
  __shared__ f16 As[64 * 136];   // 272B row stride
  int tid = threadIdx.x;
  int row0 = blockIdx.x * 64;
#pragma unroll
  for (int it = 0; it < 8; it++) {
    int idx = it * 256 + tid;          // 0..2047
    int r = idx >> 5, c4 = (idx & 31) * 4;
    int gr = row0 + r; if (gr >= n) gr = n - 1;
    float4 v = *(const float4*)&A[(size_t)gr * 128 + c4];
    if (scsh) {
      v.x = fmaxf(v.x * scsh[c4 + 0] + scsh[128 + c4 + 0], 0.f);
      v.y = fmaxf(v.y * scsh[c4 + 1] + scsh[128 + c4 + 1], 0.f);
      v.z = fmaxf(v.z * scsh[c4 + 2] + scsh[128 + c4 + 2], 0.f);
      v.w = fmaxf(v.w * scsh[c4 + 3] + scsh[128 + c4 + 3], 0.f);
    }
    h4 hv; hv[0] = (f16)v.x; hv[1] = (f16)v.y; hv[2] = (f16)v.z; hv[3] = (f16)v.w;
    *(h4*)&As[r * 136 + c4] = hv;
  }
  __syncthreads();
  int w = tid >> 6, lane = tid & 63, li = lane & 15, kg = lane >> 4;
  f32x4 acc[4][2];
#pragma unroll
  for (int mt = 0; mt < 4; mt++)
#pragma unroll
    for (int ntl = 0; ntl < 2; ntl++)
#pragma unroll
      for (int q = 0; q < 4; q++) acc[mt][ntl][q] = 0.f;
#pragma unroll
  for (int ks = 0; ks < 4; ks++) {
    h8 a[4];
#pragma unroll
    for (int mt = 0; mt < 4; mt++)
      a[mt] = *(const h8*)&As[(mt * 16 + li) * 136 + kg * 8 + ks * 32];
#pragma unroll
    for (int ntl = 0; ntl < 2; ntl++) {
      int nt = 2 * w + ntl;
      h8 b = *(const h8*)&WF[((size_t)(nt * 4 + ks) * 64 + lane) * 8];
#pragma unroll
      for (int mt = 0; mt < 4; mt++)
        acc[mt][ntl] = __builtin_amdgcn_mfma_f32_16x16x32_f16(a[mt], b, acc[mt][ntl], 0, 0, 0);
    }
  }
  __syncthreads();
#pragma unroll
  for (int mt = 0; mt < 4; mt++)
#pragma unroll
    for (int ntl = 0; ntl < 2; ntl++)
#pragma unroll
      for (int r = 0; r < 4; r++)
        As[(mt * 16 + kg * 4 + r) * 136 + (2 * w + ntl) * 16 + li] = (f16)acc[mt][ntl][r];
  __syncthreads();
#pragma unroll
  for (int it = 0; it < 4; it++) {
    int idx = it * 256 + tid;          // 0..1023
    int r = idx >> 4, c8 = (idx & 15) * 8;
    int gr = row0 + r;
    if (gr < n) *(h8*)&outh[(size_t)gr * 128 + c8] = *(const h8*)&As[r * 136 + c8];
  }
}

// ---------------- CSR gather aggregation (fp16 rows, fp32 accum) ----------------

__global__ __launch_bounds__(256) void agg_h_k(const f16* __restrict__ th, const float* __restrict__ dinv,
                                               const int* __restrict__ offs, const int* __restrict__ csr,
                                               const float* __restrict__ csrc,
                                               const float* __restrict__ bias, float* __restrict__ out, int n) {
  int node = blockIdx.x * 4 + (threadIdx.x >> 6);
  if (node >= n) return;
  int lane = threadIdx.x & 63;
  const u32* hu = (const u32*)th;
  float di = dinv[node];
  int e0 = offs[node], e1 = offs[node + 1];
  union CV { u32 u; f16 h[2]; };
  float a0x = 0.f, a0y = 0.f, a1x = 0.f, a1y = 0.f;
  float a2x = 0.f, a2y = 0.f, a3x = 0.f, a3y = 0.f;
  int e = e0;
  for (; e + 4 <= e1; e += 4) {
    int s0 = csr[e], s1 = csr[e + 1], s2 = csr[e + 2], s3 = csr[e + 3];
    float c0 = csrc[e], c1 = csrc[e + 1], c2 = csrc[e + 2], c3 = csrc[e + 3];
    CV v0, v1, v2, v3;
    v0.u = hu[(size_t)s0 * 64 + lane];
    v1.u = hu[(size_t)s1 * 64 + lane];
    v2.u = hu[(size_t)s2 * 64 + lane];
    v3.u = hu[(size_t)s3 * 64 + lane];
    a0x += c0 * (float)v0.h[0]; a0y += c0 * (float)v0.h[1];
    a1x += c1 * (float)v1.h[0]; a1y += c1 * (float)v1.h[1];
    a2x += c2 * (float)v2.h[0]; a2y += c2 * (float)v2.h[1];
    a3x += c3 * (float)v3.h[0]; a3y += c3 * (float)v3.h[1];
  }
  for (; e < e1; e++) {
    int s0 = csr[e];
    float c0 = csrc[e];
    CV v0; v0.u = hu[(size_t)s0 * 64 + lane];
    a0x += c0 * (float)v0.h[0]; a0y += c0 * (float)v0.h[1];
  }
  float sx = (a0x + a1x) + (a2x + a3x);
  float sy = (a0y + a1y) + (a2y + a3y);
  CV vs; vs.u = hu[(size_t)node * 64 + lane];
  float sc = di * di;
  float rx = di * sx + sc * (float)vs.h[0] + bias[lane * 2];
  float ry = di * sy + sc * (float)vs.h[1] + bias[lane * 2 + 1];
  float2 r; r.x = rx; r.y = ry;
  *(float2*)&out[(size_t)node * 128 + lane * 2] = r;
}

// ---------------- batchnorm ----------------

__global__ __launch_bounds__(256) void bn_stats_k(const float* __restrict__ h, float* __restrict__ sums, int n) {
  __shared__ float red[512];
  int tid = threadIdx.x;
  int c = tid & 127, half = tid >> 7;
  float s = 0.f, s2 = 0.f;
  for (int r = blockIdx.x * 2 + half; r < n; r += gridDim.x * 2) {
    float v = h[(size_t)r * 128 + c];
    s += v; s2 += v * v;
  }
  red[tid] = s; red[256 + tid] = s2;
  __syncthreads();
  if (half == 0) {
    s  = red[tid] + red[tid + 128];
    s2 = red[256 + tid] + red[256 + tid + 128];
    atomicAdd(&sums[c], s);
    atomicAdd(&sums[128 + c], s2);
  }
}

__global__ __launch_bounds__(128) void bn_fin_k(const float* __restrict__ sums, const float* __restrict__ gamma,
                                                const float* __restrict__ beta, float* __restrict__ scsh) {
  int c = threadIdx.x;
  const float inv_n = 1.0f / (float)N_NODES;
  float mean = sums[c] * inv_n;
  float var = sums[128 + c] * inv_n - mean * mean;
  float sc = gamma[c] * rsqrtf(var + 1e-5f);
  scsh[c] = sc;
  scsh[128 + c] = beta[c] - mean * sc;
}

// layer-2 BN+ReLU, emit bf16 (classifier input)
__global__ __launch_bounds__(256) void bn_apply_bf16_k(const float* __restrict__ h, const float* __restrict__ scsh,
                                                       u16* __restrict__ hb) {
  int idx = blockIdx.x * 256 + threadIdx.x;
  int c0 = (idx & 31) * 4;
  float4 v = *(const float4*)&h[(size_t)idx * 4];
  ushort4 o;
  o.x = f2bf(fmaxf(v.x * scsh[c0 + 0] + scsh[128 + c0 + 0], 0.f));
  o.y = f2bf(fmaxf(v.y * scsh[c0 + 1] + scsh[128 + c0 + 1], 0.f));
  o.z = f2bf(fmaxf(v.z * scsh[c0 + 2] + scsh[128 + c0 + 2], 0.f));
  o.w = f2bf(fmaxf(v.w * scsh[c0 + 3] + scsh[128 + c0 + 3], 0.f));
  *(ushort4*)&hb[(size_t)idx * 4] = o;
}

// ---------------- fused pair classifier (bf16 MFMA) ----------------
// 64 pairs/block, 4 waves. comb[64x256]bf16 (528B rows), z1[64x128]bf16 (272B),
// z2[64x64]bf16 (144B, aliases comb). Weights pre-packed frag-linear.

#define SM_Z1 33792
#define SM_TOT (33792 + 17408)

__global__ __launch_bounds__(256) void classifier_k(const u16* __restrict__ hbf, const int* __restrict__ pairs,
    const u16* __restrict__ Wc1F, const float* __restrict__ bc1,
    const u16* __restrict__ Wc2F, const float* __restrict__ bc2,
    const u16* __restrict__ Wc3F, const float* __restrict__ bc3,
    float* __restrict__ out) {
  __shared__ __align__(16) char smem[SM_TOT];
  __shared__ int nodes[128];
  int tid = threadIdx.x;
  int p0 = blockIdx.x * 64;
  if (tid < 128) {
    int gi = p0 * 2 + tid;
    nodes[tid] = (gi < NPAIRS * 2) ? pairs[gi] : 0;
  }
  __syncthreads();
  int w = tid >> 6, lane = tid & 63;
  int li = lane & 15, kg = lane >> 4;

  // gather 128 node halves -> comb (row-major bf16, 528B pair stride)
  {
    unsigned int* cmb = (unsigned int*)smem;
    for (int s = w * 32; s < w * 32 + 32; s++) {
      int nd = nodes[s];
      unsigned int v = ((const unsigned int*)hbf)[(size_t)nd * 64 + lane];
      cmb[(s >> 1) * 132 + (s & 1) * 64 + lane] = v;
    }
  }
  __syncthreads();

  // phase 1: z1 = relu(comb @ Wc1 + bc1)   M=64 K=256 N=128; wave -> N-tiles {2w,2w+1}
  {
    f32x4 acc[4][2];
#pragma unroll
    for (int ntl = 0; ntl < 2; ntl++) {
      float b = bc1[(2 * w + ntl) * 16 + li];
#pragma unroll
      for (int mt = 0; mt < 4; mt++)
#pragma unroll
        for (int q = 0; q < 4; q++) acc[mt][ntl][q] = b;
    }
    for (int ks = 0; ks < 8; ks++) {
      short8v a[4];
#pragma unroll
      for (int mt = 0; mt < 4; mt++)
        a[mt] = *(const short8v*)(smem + (mt * 16 + li) * 528 + kg * 16 + ks * 64);
#pragma unroll
      for (int ntl = 0; ntl < 2; ntl++) {
        int nt = 2 * w + ntl;
        short8v b = *(const short8v*)(Wc1F + ((size_t)(nt * 8 + ks) * 64 + lane) * 8);
#pragma unroll
        for (int mt = 0; mt < 4; mt++)
          acc[mt][ntl] = __builtin_amdgcn_mfma_f32_16x16x32_bf16(a[mt], b, acc[mt][ntl], 0, 0, 0);
      }
    }
#pragma unroll
    for (int mt = 0; mt < 4; mt++)
#pragma unroll
      for (int ntl = 0; ntl < 2; ntl++)
#pragma unroll
        for (int r = 0; r < 4; r++) {
          int row = mt * 16 + kg * 4 + r;
          int col = (2 * w + ntl) * 16 + li;
          *(u16*)(smem + SM_Z1 + row * 272 + col * 2) = f2bf(fmaxf(acc[mt][ntl][r], 0.f));
        }
  }
  __syncthreads();

  // phase 2: z2 = relu(z1 @ Wc2 + bc2)   M=64 K=128 N=64; wave -> N-tile w
  {
    f32x4 acc[4];
    float b = bc2[w * 16 + li];
#pragma unroll
    for (int mt = 0; mt < 4; mt++)
#pragma unroll
      for (int q = 0; q < 4; q++) acc[mt][q] = b;
    for (int ks = 0; ks < 4; ks++) {
      short8v a[4];
#pragma unroll
      for (int mt = 0; mt < 4; mt++)
        a[mt] = *(const short8v*)(smem + SM_Z1 + (mt * 16 + li) * 272 + kg * 16 + ks * 64);
      short8v bf = *(const short8v*)(Wc2F + ((size_t)(w * 4 + ks) * 64 + lane) * 8);
#pragma unroll
      for (int mt = 0; mt < 4; mt++)
        acc[mt] = __builtin_amdgcn_mfma_f32_16x16x32_bf16(a[mt], bf, acc[mt], 0, 0, 0);
    }
#pragma unroll
    for (int mt = 0; mt < 4; mt++)
#pragma unroll
      for (int r = 0; r < 4; r++) {
        int row = mt * 16 + kg * 4 + r;
        int col = w * 16 + li;
        *(u16*)(smem + row * 144 + col * 2) = f2bf(fmaxf(acc[mt][r], 0.f));
      }
  }
  __syncthreads();

  // phase 3: out = z2 @ Wc3 + bc3   M=64 K=64 N=86 (padded 128); wave -> N-tiles {2w,2w+1}
  {
    f32x4 acc[4][2];
#pragma unroll
    for (int ntl = 0; ntl < 2; ntl++) {
      int col = (2 * w + ntl) * 16 + li;
      float b = (col < 86) ? bc3[col] : 0.f;
#pragma unroll
      for (int mt = 0; mt < 4; mt++)
#pragma unroll
        for (int q = 0; q < 4; q++) acc[mt][ntl][q] = b;
    }
    for (int ks = 0; ks < 2; ks++) {
      short8v a[4];
#pragma unroll
      for (int mt = 0; mt < 4; mt++)
        a[mt] = *(const short8v*)(smem + (mt * 16 + li) * 144 + kg * 16 + ks * 64);
#pragma unroll
      for (int ntl = 0; ntl < 2; ntl++) {
        int nt = 2 * w + ntl;
        short8v bf = *(const short8v*)(Wc3F + ((size_t)(nt * 2 + ks) * 64 + lane) * 8);
#pragma unroll
        for (int mt = 0; mt < 4; mt++)
          acc[mt][ntl] = __builtin_amdgcn_mfma_f32_16x16x32_bf16(a[mt], bf, acc[mt][ntl], 0, 0, 0);
      }
    }
#pragma unroll
    for (int mt = 0; mt < 4; mt++)
#pragma unroll
      for (int ntl = 0; ntl < 2; ntl++) {
        int col = (2 * w + ntl) * 16 + li;
        if (col < 86) {
#pragma unroll
          for (int r = 0; r < 4; r++) {
            int row = p0 + mt * 16 + kg * 4 + r;
            if (row < NPAIRS) out[(size_t)row * 86 + col] = acc[mt][ntl][r];
          }
        }
      }
  }
}

// ---------------- launch ----------------

extern "C" void kernel_launch(void* const* d_in, const int* in_sizes, int n_in,
                              void* d_out, int out_size, void* d_ws, size_t ws_size,
                              hipStream_t stream) {
  (void)in_sizes; (void)n_in; (void)out_size; (void)ws_size;
  const float* x   = (const float*)d_in[0];
  const int*   ei  = (const int*)d_in[1];
  const int* pairs = (const int*)d_in[2];
  const float* W1  = (const float*)d_in[3];
  const float* b1  = (const float*)d_in[4];
  const float* g1  = (const float*)d_in[5];
  const float* be1 = (const float*)d_in[6];
  const float* W2  = (const float*)d_in[7];
  const float* b2  = (const float*)d_in[8];
  const float* g2  = (const float*)d_in[9];
  const float* be2 = (const float*)d_in[10];
  const float* Wc1 = (const float*)d_in[11];
  const float* bc1 = (const float*)d_in[12];
  const float* Wc2 = (const float*)d_in[13];
  const float* bc2 = (const float*)d_in[14];
  const float* Wc3 = (const float*)d_in[15];
  const float* bc3 = (const float*)d_in[16];
  float* out = (float*)d_out;

  size_t off = 0;
  auto alloc = [&](size_t bytes) -> char* {
    char* p = (char*)d_ws + off;
    off += (bytes + 255) & ~(size_t)255;
    return p;
  };
  int* deg      = (int*)alloc(N_NODES * 4);
  int* cursor   = (int*)alloc(N_NODES * 4);
  float* sums1  = (float*)alloc(256 * 4);
  float* sums2  = (float*)alloc(256 * 4);
  size_t zero_span = off;
  int* offs     = (int*)alloc((N_NODES + 1) * 4);
  int* csr      = (int*)alloc(N_EDGES * 4);
  float* csrc   = (float*)alloc(N_EDGES * 4);
  float* dinv   = (float*)alloc(N_NODES * 4);
  float* scsh1  = (float*)alloc(256 * 4);
  float* scsh2  = (float*)alloc(256 * 4);
  f16* W1F      = (f16*)alloc(2048 * 8 * 2);
  f16* W2F      = (f16*)alloc(2048 * 8 * 2);
  u16* Wc1F     = (u16*)alloc(4096 * 8 * 2);
  u16* Wc2F     = (u16*)alloc(1024 * 8 * 2);
  u16* Wc3F     = (u16*)alloc(1024 * 8 * 2);
  float* bufB   = (float*)alloc((size_t)N_NODES * 128 * 4);
  f16* th       = (f16*)alloc((size_t)N_NODES * 128 * 2);
  u16* hbf      = (u16*)th;   // aliases th (t2 dead when written)

  hipMemsetAsync(d_ws, 0, zero_span, stream);
  deg_count_k<<<(N_EDGES + 255) / 256, 256, 0, stream>>>(ei, deg, N_EDGES);
  dinv_k<<<(N_NODES + 255) / 256, 256, 0, stream>>>(deg, dinv, N_NODES);
  scan_k<<<1, 1024, 0, stream>>>(deg, offs, N_NODES);
  fill_k<<<(N_EDGES + 255) / 256, 256, 0, stream>>>(ei, offs, cursor, csr, csrc, dinv, N_EDGES);
  prep_w_k<<<40, 256, 0, stream>>>(W1, W2, Wc1, Wc2, Wc3, W1F, W2F, Wc1F, Wc2F, Wc3F);

  // layer 1: t1 = x @ W1 (fp16 out); agg; BN stats
  gemm_mfma_k<<<(N_NODES + 63) / 64, 256, 0, stream>>>(x, nullptr, W1F, th, N_NODES);
  agg_h_k<<<N_NODES / 4, 256, 0, stream>>>(th, dinv, offs, csr, csrc, b1, bufB, N_NODES);
  bn_stats_k<<<256, 256, 0, stream>>>(bufB, sums1, N_NODES);
  bn_fin_k<<<1, 128, 0, stream>>>(sums1, g1, be1, scsh1);

  // layer 2: t2 = bnrelu(h1) @ W2 (BN fused into staging); agg; BN stats
  gemm_mfma_k<<<(N_NODES + 63) / 64, 256, 0, stream>>>(bufB, scsh1, W2F, th, N_NODES);
  agg_h_k<<<N_NODES / 4, 256, 0, stream>>>(th, dinv, offs, csr, csrc, b2, bufB, N_NODES);
  bn_stats_k<<<256, 256, 0, stream>>>(bufB, sums2, N_NODES);
  bn_fin_k<<<1, 128, 0, stream>>>(sums2, g2, be2, scsh2);
  bn_apply_bf16_k<<<N_NODES / 8, 256, 0, stream>>>(bufB, scsh2, hbf);

  // classifier
  classifier_k<<<(NPAIRS + 63) / 64, 256, 0, stream>>>(hbf, pairs, Wc1F, bc1, Wc2F, bc2, Wc3F, bc3, out);
}

// Round 5
// 390.196 us; speedup vs baseline: 2.3646x; 1.0184x over previous
//
#include <hip/hip_runtime.h>
#include <cstdint>

#define N_NODES 50000
#define N_EDGES 800000
#define NPAIRS  100000

typedef unsigned short u16;
typedef unsigned int u32;
typedef _Float16 f16;
typedef short short8v __attribute__((ext_vector_type(8)));
typedef _Float16 h8 __attribute__((ext_vector_type(8)));
typedef _Float16 h4 __attribute__((ext_vector_type(4)));
typedef float f32x4 __attribute__((ext_vector_type(4)));

static __device__ __forceinline__ u16 f2bf(float f) {
  unsigned int u = __float_as_uint(f);
  u += 0x7FFF + ((u >> 16) & 1);
  return (u16)(u >> 16);
}

static __device__ __forceinline__ float bits2f(u32 hi) {
  union { u16 b; f16 h; } x;
  x.b = (u16)hi;
  return (float)x.h;
}

// ---------------- preprocessing: degree-count + rank + weight packing ----------------

__global__ __launch_bounds__(256) void pre_k(const int* __restrict__ ei, int* __restrict__ deg, int* __restrict__ rank,
                                             const float* __restrict__ W1, const float* __restrict__ W2,
                                             const float* __restrict__ Wc1, const float* __restrict__ Wc2,
                                             const float* __restrict__ Wc3,
                                             f16* __restrict__ W1F, f16* __restrict__ W2F,
                                             u16* __restrict__ Wc1F, u16* __restrict__ Wc2F, u16* __restrict__ Wc3F) {
  int b = blockIdx.x;
  if (b < N_EDGES / 256) {
    int e = b * 256 + threadIdx.x;
    rank[e] = atomicAdd(&deg[ei[N_EDGES + e]], 1);
    return;
  }
  int slot = (b - N_EDGES / 256) * 256 + threadIdx.x;
  int lane = slot & 63, j = lane & 15, kg = lane >> 4;
  if (slot < 2048) {           // W1: K=128, N=128 (fp16)
    int ks = (slot >> 6) & 3, nt = slot >> 8;
    int k0 = ks * 32 + kg * 8, c = nt * 16 + j;
#pragma unroll
    for (int e = 0; e < 8; e++) W1F[(size_t)slot * 8 + e] = (f16)W1[(k0 + e) * 128 + c];
  } else if (slot < 4096) {    // W2: K=128, N=128 (fp16)
    int s2 = slot - 2048;
    int ks = (s2 >> 6) & 3, nt = s2 >> 8;
    int k0 = ks * 32 + kg * 8, c = nt * 16 + j;
#pragma unroll
    for (int e = 0; e < 8; e++) W2F[(size_t)s2 * 8 + e] = (f16)W2[(k0 + e) * 128 + c];
  } else if (slot < 8192) {    // Wc1: K=256, N=128 (bf16)
    int s3 = slot - 4096;
    int ks = (s3 >> 6) & 7, nt = s3 >> 9;
    int k0 = ks * 32 + kg * 8, c = nt * 16 + j;
#pragma unroll
    for (int e = 0; e < 8; e++) Wc1F[(size_t)s3 * 8 + e] = f2bf(Wc1[(k0 + e) * 128 + c]);
  } else if (slot < 9216) {    // Wc2: K=128, N=64 (bf16)
    int s4 = slot - 8192;
    int ks = (s4 >> 6) & 3, nt = s4 >> 8;
    int k0 = ks * 32 + kg * 8, c = nt * 16 + j;
#pragma unroll
    for (int e = 0; e < 8; e++) Wc2F[(size_t)s4 * 8 + e] = f2bf(Wc2[(k0 + e) * 64 + c]);
  } else if (slot < 10240) {   // Wc3: K=64, N=86 padded 128 (bf16)
    int s5 = slot - 9216;
    int ks = (s5 >> 6) & 1, nt = s5 >> 7;
    int k0 = ks * 32 + kg * 8, c = nt * 16 + j;
#pragma unroll
    for (int e = 0; e < 8; e++)
      Wc3F[(size_t)s5 * 8 + e] = f2bf((c < 86) ? Wc3[(k0 + e) * 86 + c] : 0.f);
  }
}

// single-block exclusive scan (4 elems/thread) + dinv = rsqrt(deg+1)
__global__ __launch_bounds__(1024) void scan_k(const int* __restrict__ deg, int* __restrict__ offs,
                                               float* __restrict__ dinv, int n) {
  __shared__ int wsum[16];
  __shared__ int wpre[16];
  __shared__ int run_s;
  int tid = threadIdx.x, lane = tid & 63, wid = tid >> 6;
  if (tid == 0) run_s = 0;
  __syncthreads();
  for (int base = 0; base < n; base += 4096) {
    int i4 = base + tid * 4;
    int4 v = make_int4(0, 0, 0, 0);
    if (i4 + 3 < n) v = *(const int4*)&deg[i4];
    else {
      if (i4 < n) v.x = deg[i4];
      if (i4 + 1 < n) v.y = deg[i4 + 1];
      if (i4 + 2 < n) v.z = deg[i4 + 2];
      if (i4 + 3 < n) v.w = deg[i4 + 3];
    }
    int tsum = v.x + v.y + v.z + v.w;
    int s = tsum;
#pragma unroll
    for (int d = 1; d < 64; d <<= 1) {
      int t = __shfl_up(s, d);
      if (lane >= d) s += t;
    }
    if (lane == 63) wsum[wid] = s;
    __syncthreads();
    if (tid == 0) {
      int acc = run_s;
#pragma unroll
      for (int w = 0; w < 16; w++) { wpre[w] = acc; acc += wsum[w]; }
      run_s = acc;
    }
    __syncthreads();
    int pre = wpre[wid] + (s - tsum);
    int4 o;
    o.x = pre; o.y = pre + v.x; o.z = o.y + v.y; o.w = o.z + v.z;
    float4 dv;
    dv.x = rsqrtf((float)v.x + 1.0f);
    dv.y = rsqrtf((float)v.y + 1.0f);
    dv.z = rsqrtf((float)v.z + 1.0f);
    dv.w = rsqrtf((float)v.w + 1.0f);
    if (i4 + 3 < n) {
      *(int4*)&offs[i4] = o;
      *(float4*)&dinv[i4] = dv;
    } else {
      if (i4 < n)     { offs[i4] = o.x;     dinv[i4] = dv.x; }
      if (i4 + 1 < n) { offs[i4 + 1] = o.y; dinv[i4 + 1] = dv.y; }
      if (i4 + 2 < n) { offs[i4 + 2] = o.z; dinv[i4 + 2] = dv.z; }
      if (i4 + 3 < n) { offs[i4 + 3] = o.w; dinv[i4 + 3] = dv.w; }
    }
    __syncthreads();
  }
  if (tid == 0) offs[n] = run_s;
}

// CSR placement, atomic-free: idx = offs[dst] + rank[e]; one packed u32 per edge.
__global__ __launch_bounds__(256) void fill_k(const int* __restrict__ ei, const int* __restrict__ offs,
                                              const int* __restrict__ rank, const float* __restrict__ dinv,
                                              u32* __restrict__ csrp, int E) {
  int e = blockIdx.x * 256 + threadIdx.x;
  if (e < E) {
    int s = ei[e], d = ei[E + e];
    int idx = offs[d] + rank[e];
    f16 hv = (f16)dinv[s];
    u32 pack = (u32)(u16)s | ((u32)(*(u16*)&hv) << 16);
    csrp[idx] = pack;
  }
}

// ---------------- fp16 MFMA node GEMM ----------------
// MODE 0: A fp32, no BN.  MODE 1: A fp16, BN(scale/shift from sums,gamma,beta)+ReLU fused into staging.

template<int MODE>
__global__ __launch_bounds__(256) void gemm_mfma_k(const void* __restrict__ Ain,
                                                   const float* __restrict__ sums,
                                                   const float* __restrict__ gamma,
                                                   const float* __restrict__ beta,
                                                   const f16* __restrict__ WF,
                                                   f16* __restrict__ outh, int n) {
  __shared__ f16 As[64 * 136];   // 272B row stride
  __shared__ float scsh[256];
  int tid = threadIdx.x;
  if (MODE == 1) {
    if (tid < 128) {
      const float inv_n = 1.0f / (float)N_NODES;
      float mean = sums[tid] * inv_n;
      float var = sums[128 + tid] * inv_n - mean * mean;
      float sc = gamma[tid] * rsqrtf(var + 1e-5f);
      scsh[tid] = sc;
      scsh[128 + tid] = beta[tid] - mean * sc;
    }
    __syncthreads();
  }
  int row0 = blockIdx.x * 64;
#pragma unroll
  for (int it = 0; it < 8; it++) {
    int idx = it * 256 + tid;          // 0..2047
    int r = idx >> 5, c4 = (idx & 31) * 4;
    int gr = row0 + r; if (gr >= n) gr = n - 1;
    float4 v;
    if (MODE == 0) {
      v = *(const float4*)&((const float*)Ain)[(size_t)gr * 128 + c4];
    } else {
      h4 hv4 = *(const h4*)&((const f16*)Ain)[(size_t)gr * 128 + c4];
      v.x = (float)hv4[0]; v.y = (float)hv4[1]; v.z = (float)hv4[2]; v.w = (float)hv4[3];
      v.x = fmaxf(v.x * scsh[c4 + 0] + scsh[128 + c4 + 0], 0.f);
      v.y = fmaxf(v.y * scsh[c4 + 1] + scsh[128 + c4 + 1], 0.f);
      v.z = fmaxf(v.z * scsh[c4 + 2] + scsh[128 + c4 + 2], 0.f);
      v.w = fmaxf(v.w * scsh[c4 + 3] + scsh[128 + c4 + 3], 0.f);
    }
    h4 hv; hv[0] = (f16)v.x; hv[1] = (f16)v.y; hv[2] = (f16)v.z; hv[3] = (f16)v.w;
    *(h4*)&As[r * 136 + c4] = hv;
  }
  __syncthreads();
  int w = tid >> 6, lane = tid & 63, li = lane & 15, kg = lane >> 4;
  f32x4 acc[4][2];
#pragma unroll
  for (int mt = 0; mt < 4; mt++)
#pragma unroll
    for (int ntl = 0; ntl < 2; ntl++)
#pragma unroll
      for (int q = 0; q < 4; q++) acc[mt][ntl][q] = 0.f;
#pragma unroll
  for (int ks = 0; ks < 4; ks++) {
    h8 a[4];
#pragma unroll
    for (int mt = 0; mt < 4; mt++)
      a[mt] = *(const h8*)&As[(mt * 16 + li) * 136 + kg * 8 + ks * 32];
#pragma unroll
    for (int ntl = 0; ntl < 2; ntl++) {
      int nt = 2 * w + ntl;
      h8 b = *(const h8*)&WF[((size_t)(nt * 4 + ks) * 64 + lane) * 8];
#pragma unroll
      for (int mt = 0; mt < 4; mt++)
        acc[mt][ntl] = __builtin_amdgcn_mfma_f32_16x16x32_f16(a[mt], b, acc[mt][ntl], 0, 0, 0);
    }
  }
  __syncthreads();
#pragma unroll
  for (int mt = 0; mt < 4; mt++)
#pragma unroll
    for (int ntl = 0; ntl < 2; ntl++)
#pragma unroll
      for (int r = 0; r < 4; r++)
        As[(mt * 16 + kg * 4 + r) * 136 + (2 * w + ntl) * 16 + li] = (f16)acc[mt][ntl][r];
  __syncthreads();
#pragma unroll
  for (int it = 0; it < 4; it++) {
    int idx = it * 256 + tid;          // 0..1023
    int r = idx >> 4, c8 = (idx & 15) * 8;
    int gr = row0 + r;
    if (gr < n) *(h8*)&outh[(size_t)gr * 128 + c8] = *(const h8*)&As[r * 136 + c8];
  }
}

// ---------------- CSR gather aggregation (fp16, packed coeff) + fused BN stats ----------------

__global__ __launch_bounds__(256) void agg_h_k(const f16* __restrict__ th, const float* __restrict__ dinv,
                                               const int* __restrict__ offs, const u32* __restrict__ csrp,
                                               const float* __restrict__ bias, f16* __restrict__ outh,
                                               float* __restrict__ sums, int n) {
  int tid = threadIdx.x;
  int lane = tid & 63, w = tid >> 6;
  const u32* hu = (const u32*)th;
  u32* ou = (u32*)outh;
  float bx = bias[lane * 2], by = bias[lane * 2 + 1];
  float s1x = 0.f, s1y = 0.f, q1x = 0.f, q1y = 0.f;
  union CV { u32 u; f16 h[2]; };
  for (int node = blockIdx.x * 4 + w; node < n; node += gridDim.x * 4) {
    float di = dinv[node];
    int e0 = offs[node], e1 = offs[node + 1];
    float a0x = 0.f, a0y = 0.f, a1x = 0.f, a1y = 0.f;
    float a2x = 0.f, a2y = 0.f, a3x = 0.f, a3y = 0.f;
    int e = e0;
    for (; e + 4 <= e1; e += 4) {
      u32 p0 = csrp[e], p1 = csrp[e + 1], p2 = csrp[e + 2], p3 = csrp[e + 3];
      float c0 = bits2f(p0 >> 16), c1 = bits2f(p1 >> 16);
      float c2 = bits2f(p2 >> 16), c3 = bits2f(p3 >> 16);
      CV v0, v1, v2, v3;
      v0.u = hu[(size_t)(p0 & 0xFFFF) * 64 + lane];
      v1.u = hu[(size_t)(p1 & 0xFFFF) * 64 + lane];
      v2.u = hu[(size_t)(p2 & 0xFFFF) * 64 + lane];
      v3.u = hu[(size_t)(p3 & 0xFFFF) * 64 + lane];
      a0x += c0 * (float)v0.h[0]; a0y += c0 * (float)v0.h[1];
      a1x += c1 * (float)v1.h[0]; a1y += c1 * (float)v1.h[1];
      a2x += c2 * (float)v2.h[0]; a2y += c2 * (float)v2.h[1];
      a3x += c3 * (float)v3.h[0]; a3y += c3 * (float)v3.h[1];
    }
    for (; e < e1; e++) {
      u32 p0 = csrp[e];
      float c0 = bits2f(p0 >> 16);
      CV v0; v0.u = hu[(size_t)(p0 & 0xFFFF) * 64 + lane];
      a0x += c0 * (float)v0.h[0]; a0y += c0 * (float)v0.h[1];
    }
    float sx = (a0x + a1x) + (a2x + a3x);
    float sy = (a0y + a1y) + (a2y + a3y);
    CV vs; vs.u = hu[(size_t)node * 64 + lane];
    float sc = di * di;
    float rx = di * sx + sc * (float)vs.h[0] + bx;
    float ry = di * sy + sc * (float)vs.h[1] + by;
    CV o; o.h[0] = (f16)rx; o.h[1] = (f16)ry;
    ou[(size_t)node * 64 + lane] = o.u;
    s1x += rx; q1x += rx * rx;
    s1y += ry; q1y += ry * ry;
  }
  __shared__ float rsum[4][128];
  __shared__ float rsq[4][128];
  rsum[w][lane * 2] = s1x; rsum[w][lane * 2 + 1] = s1y;
  rsq[w][lane * 2] = q1x;  rsq[w][lane * 2 + 1] = q1y;
  __syncthreads();
  if (tid < 128) {
    float a = (rsum[0][tid] + rsum[1][tid]) + (rsum[2][tid] + rsum[3][tid]);
    float b = (rsq[0][tid] + rsq[1][tid]) + (rsq[2][tid] + rsq[3][tid]);
    atomicAdd(&sums[tid], a);
    atomicAdd(&sums[128 + tid], b);
  }
}

// ---------------- layer-2 BN+ReLU (scale/shift computed in-block), emit bf16 ----------------

__global__ __launch_bounds__(256) void bn_apply_bf16_k(const f16* __restrict__ h, const float* __restrict__ sums,
                                                       const float* __restrict__ gamma, const float* __restrict__ beta,
                                                       u16* __restrict__ hb) {
  __shared__ float scsh[256];
  int tid = threadIdx.x;
  if (tid < 128) {
    const float inv_n = 1.0f / (float)N_NODES;
    float mean = sums[tid] * inv_n;
    float var = sums[128 + tid] * inv_n - mean * mean;
    float sc = gamma[tid] * rsqrtf(var + 1e-5f);
    scsh[tid] = sc;
    scsh[128 + tid] = beta[tid] - mean * sc;
  }
  __syncthreads();
  int idx = blockIdx.x * 256 + tid;
  int c0 = (idx & 31) * 4;
  h4 v4 = *(const h4*)&h[(size_t)idx * 4];
  ushort4 o;
  o.x = f2bf(fmaxf((float)v4[0] * scsh[c0 + 0] + scsh[128 + c0 + 0], 0.f));
  o.y = f2bf(fmaxf((float)v4[1] * scsh[c0 + 1] + scsh[128 + c0 + 1], 0.f));
  o.z = f2bf(fmaxf((float)v4[2] * scsh[c0 + 2] + scsh[128 + c0 + 2], 0.f));
  o.w = f2bf(fmaxf((float)v4[3] * scsh[c0 + 3] + scsh[128 + c0 + 3], 0.f));
  *(ushort4*)&hb[(size_t)idx * 4] = o;
}

// ---------------- fused pair classifier (bf16 MFMA) ----------------
// 64 pairs/block, 4 waves. comb[64x256]bf16 (528B rows), z1[64x128]bf16 (272B),
// z2[64x64]bf16 (144B, aliases comb). Weights pre-packed frag-linear.

#define SM_Z1 33792
#define SM_TOT (33792 + 17408)

__global__ __launch_bounds__(256) void classifier_k(const u16* __restrict__ hbf, const int* __restrict__ pairs,
    const u16* __restrict__ Wc1F, const float* __restrict__ bc1,
    const u16* __restrict__ Wc2F, const float* __restrict__ bc2,
    const u16* __restrict__ Wc3F, const float* __restrict__ bc3,
    float* __restrict__ out) {
  __shared__ __align__(16) char smem[SM_TOT];
  __shared__ int nodes[128];
  int tid = threadIdx.x;
  int p0 = blockIdx.x * 64;
  if (tid < 128) {
    int gi = p0 * 2 + tid;
    nodes[tid] = (gi < NPAIRS * 2) ? pairs[gi] : 0;
  }
  __syncthreads();
  int w = tid >> 6, lane = tid & 63;
  int li = lane & 15, kg = lane >> 4;

  // gather 128 node halves -> comb (row-major bf16, 528B pair stride)
  {
    unsigned int* cmb = (unsigned int*)smem;
    for (int s = w * 32; s < w * 32 + 32; s++) {
      int nd = nodes[s];
      unsigned int v = ((const unsigned int*)hbf)[(size_t)nd * 64 + lane];
      cmb[(s >> 1) * 132 + (s & 1) * 64 + lane] = v;
    }
  }
  __syncthreads();

  // phase 1: z1 = relu(comb @ Wc1 + bc1)   M=64 K=256 N=128; wave -> N-tiles {2w,2w+1}
  {
    f32x4 acc[4][2];
#pragma unroll
    for (int ntl = 0; ntl < 2; ntl++) {
      float b = bc1[(2 * w + ntl) * 16 + li];
#pragma unroll
      for (int mt = 0; mt < 4; mt++)
#pragma unroll
        for (int q = 0; q < 4; q++) acc[mt][ntl][q] = b;
    }
    for (int ks = 0; ks < 8; ks++) {
      short8v a[4];
#pragma unroll
      for (int mt = 0; mt < 4; mt++)
        a[mt] = *(const short8v*)(smem + (mt * 16 + li) * 528 + kg * 16 + ks * 64);
#pragma unroll
      for (int ntl = 0; ntl < 2; ntl++) {
        int nt = 2 * w + ntl;
        short8v b = *(const short8v*)(Wc1F + ((size_t)(nt * 8 + ks) * 64 + lane) * 8);
#pragma unroll
        for (int mt = 0; mt < 4; mt++)
          acc[mt][ntl] = __builtin_amdgcn_mfma_f32_16x16x32_bf16(a[mt], b, acc[mt][ntl], 0, 0, 0);
      }
    }
#pragma unroll
    for (int mt = 0; mt < 4; mt++)
#pragma unroll
      for (int ntl = 0; ntl < 2; ntl++)
#pragma unroll
        for (int r = 0; r < 4; r++) {
          int row = mt * 16 + kg * 4 + r;
          int col = (2 * w + ntl) * 16 + li;
          *(u16*)(smem + SM_Z1 + row * 272 + col * 2) = f2bf(fmaxf(acc[mt][ntl][r], 0.f));
        }
  }
  __syncthreads();

  // phase 2: z2 = relu(z1 @ Wc2 + bc2)   M=64 K=128 N=64; wave -> N-tile w
  {
    f32x4 acc[4];
    float b = bc2[w * 16 + li];
#pragma unroll
    for (int mt = 0; mt < 4; mt++)
#pragma unroll
      for (int q = 0; q < 4; q++) acc[mt][q] = b;
    for (int ks = 0; ks < 4; ks++) {
      short8v a[4];
#pragma unroll
      for (int mt = 0; mt < 4; mt++)
        a[mt] = *(const short8v*)(smem + SM_Z1 + (mt * 16 + li) * 272 + kg * 16 + ks * 64);
      short8v bf = *(const short8v*)(Wc2F + ((size_t)(w * 4 + ks) * 64 + lane) * 8);
#pragma unroll
      for (int mt = 0; mt < 4; mt++)
        acc[mt] = __builtin_amdgcn_mfma_f32_16x16x32_bf16(a[mt], bf, acc[mt], 0, 0, 0);
    }
#pragma unroll
    for (int mt = 0; mt < 4; mt++)
#pragma unroll
      for (int r = 0; r < 4; r++) {
        int row = mt * 16 + kg * 4 + r;
        int col = w * 16 + li;
        *(u16*)(smem + row * 144 + col * 2) = f2bf(fmaxf(acc[mt][r], 0.f));
      }
  }
  __syncthreads();

  // phase 3: out = z2 @ Wc3 + bc3   M=64 K=64 N=86 (padded 128); wave -> N-tiles {2w,2w+1}
  {
    f32x4 acc[4][2];
#pragma unroll
    for (int ntl = 0; ntl < 2; ntl++) {
      int col = (2 * w + ntl) * 16 + li;
      float b = (col < 86) ? bc3[col] : 0.f;
#pragma unroll
      for (int mt = 0; mt < 4; mt++)
#pragma unroll
        for (int q = 0; q < 4; q++) acc[mt][ntl][q] = b;
    }
    for (int ks = 0; ks < 2; ks++) {
      short8v a[4];
#pragma unroll
      for (int mt = 0; mt < 4; mt++)
        a[mt] = *(const short8v*)(smem + (mt * 16 + li) * 144 + kg * 16 + ks * 64);
#pragma unroll
      for (int ntl = 0; ntl < 2; ntl++) {
        int nt = 2 * w + ntl;
        short8v bf = *(const short8v*)(Wc3F + ((size_t)(nt * 2 + ks) * 64 + lane) * 8);
#pragma unroll
        for (int mt = 0; mt < 4; mt++)
          acc[mt][ntl] = __builtin_amdgcn_mfma_f32_16x16x32_bf16(a[mt], bf, acc[mt][ntl], 0, 0, 0);
      }
    }
#pragma unroll
    for (int mt = 0; mt < 4; mt++)
#pragma unroll
      for (int ntl = 0; ntl < 2; ntl++) {
        int col = (2 * w + ntl) * 16 + li;
        if (col < 86) {
#pragma unroll
          for (int r = 0; r < 4; r++) {
            int row = p0 + mt * 16 + kg * 4 + r;
            if (row < NPAIRS) out[(size_t)row * 86 + col] = acc[mt][ntl][r];
          }
        }
      }
  }
}

// ---------------- launch ----------------

extern "C" void kernel_launch(void* const* d_in, const int* in_sizes, int n_in,
                              void* d_out, int out_size, void* d_ws, size_t ws_size,
                              hipStream_t stream) {
  (void)in_sizes; (void)n_in; (void)out_size; (void)ws_size;
  const float* x   = (const float*)d_in[0];
  const int*   ei  = (const int*)d_in[1];
  const int* pairs = (const int*)d_in[2];
  const float* W1  = (const float*)d_in[3];
  const float* b1  = (const float*)d_in[4];
  const float* g1  = (const float*)d_in[5];
  const float* be1 = (const float*)d_in[6];
  const float* W2  = (const float*)d_in[7];
  const float* b2  = (const float*)d_in[8];
  const float* g2  = (const float*)d_in[9];
  const float* be2 = (const float*)d_in[10];
  const float* Wc1 = (const float*)d_in[11];
  const float* bc1 = (const float*)d_in[12];
  const float* Wc2 = (const float*)d_in[13];
  const float* bc2 = (const float*)d_in[14];
  const float* Wc3 = (const float*)d_in[15];
  const float* bc3 = (const float*)d_in[16];
  float* out = (float*)d_out;

  size_t off = 0;
  auto alloc = [&](size_t bytes) -> char* {
    char* p = (char*)d_ws + off;
    off += (bytes + 255) & ~(size_t)255;
    return p;
  };
  int* deg      = (int*)alloc(N_NODES * 4);
  float* sums1  = (float*)alloc(256 * 4);
  float* sums2  = (float*)alloc(256 * 4);
  size_t zero_span = off;
  int* offs     = (int*)alloc((N_NODES + 1) * 4);
  int* rank     = (int*)alloc(N_EDGES * 4);
  u32* csrp     = (u32*)alloc(N_EDGES * 4);
  float* dinv   = (float*)alloc(N_NODES * 4);
  f16* W1F      = (f16*)alloc(2048 * 8 * 2);
  f16* W2F      = (f16*)alloc(2048 * 8 * 2);
  u16* Wc1F     = (u16*)alloc(4096 * 8 * 2);
  u16* Wc2F     = (u16*)alloc(1024 * 8 * 2);
  u16* Wc3F     = (u16*)alloc(1024 * 8 * 2);
  f16* th       = (f16*)alloc((size_t)N_NODES * 128 * 2);
  f16* hA       = (f16*)alloc((size_t)N_NODES * 128 * 2);
  u16* hbf      = (u16*)th;   // aliases th (t2 dead when written)

  hipMemsetAsync(d_ws, 0, zero_span, stream);
  pre_k<<<N_EDGES / 256 + 40, 256, 0, stream>>>(ei, deg, rank, W1, W2, Wc1, Wc2, Wc3,
                                                W1F, W2F, Wc1F, Wc2F, Wc3F);
  scan_k<<<1, 1024, 0, stream>>>(deg, offs, dinv, N_NODES);
  fill_k<<<N_EDGES / 256, 256, 0, stream>>>(ei, offs, rank, dinv, csrp, N_EDGES);

  // layer 1: t1 = x @ W1; agg(+stats1)
  gemm_mfma_k<0><<<(N_NODES + 63) / 64, 256, 0, stream>>>(x, nullptr, nullptr, nullptr, W1F, th, N_NODES);
  agg_h_k<<<2048, 256, 0, stream>>>(th, dinv, offs, csrp, b1, hA, sums1, N_NODES);

  // layer 2: t2 = bnrelu(h1) @ W2 (BN from sums1 fused); agg(+stats2)
  gemm_mfma_k<1><<<(N_NODES + 63) / 64, 256, 0, stream>>>(hA, sums1, g1, be1, W2F, th, N_NODES);
  agg_h_k<<<2048, 256, 0, stream>>>(th, dinv, offs, csrp, b2, hA, sums2, N_NODES);

  // BN2 + ReLU -> bf16 classifier input
  bn_apply_bf16_k<<<(N_NODES * 128) / 1024, 256, 0, stream>>>(hA, sums2, g2, be2, hbf);

  // classifier
  classifier_k<<<(NPAIRS + 63) / 64, 256, 0, stream>>>(hbf, pairs, Wc1F, bc1, Wc2F, bc2, Wc3F, bc3, out);
}

// Round 6
// 335.780 us; speedup vs baseline: 2.7479x; 1.1621x over previous
//
#include <hip/hip_runtime.h>
#include <cstdint>

#define N_NODES 50000
#define N_EDGES 800000
#define NPAIRS  100000

typedef unsigned short u16;
typedef unsigned int u32;
typedef unsigned long long u64;
typedef _Float16 f16;
typedef short short8v __attribute__((ext_vector_type(8)));
typedef _Float16 h8 __attribute__((ext_vector_type(8)));
typedef _Float16 h4 __attribute__((ext_vector_type(4)));
typedef float f32x4 __attribute__((ext_vector_type(4)));

static __device__ __forceinline__ u16 f2bf(float f) {
  unsigned int u = __float_as_uint(f);
  u += 0x7FFF + ((u >> 16) & 1);
  return (u16)(u >> 16);
}

static __device__ __forceinline__ float bits2f(u32 hi) {
  union { u16 b; f16 h; } x;
  x.b = (u16)hi;
  return (float)x.h;
}

// ---------------- preprocessing: degree-count + rank + weight packing ----------------

__global__ __launch_bounds__(256) void pre_k(const int* __restrict__ ei, int* __restrict__ deg, int* __restrict__ rank,
                                             const float* __restrict__ W1, const float* __restrict__ W2,
                                             const float* __restrict__ Wc1, const float* __restrict__ Wc2,
                                             const float* __restrict__ Wc3,
                                             f16* __restrict__ W1F, f16* __restrict__ W2F,
                                             u16* __restrict__ Wc1F, u16* __restrict__ Wc2F, u16* __restrict__ Wc3F) {
  int b = blockIdx.x;
  if (b < N_EDGES / 256) {
    int e = b * 256 + threadIdx.x;
    rank[e] = atomicAdd(&deg[ei[N_EDGES + e]], 1);
    return;
  }
  int slot = (b - N_EDGES / 256) * 256 + threadIdx.x;
  int lane = slot & 63, j = lane & 15, kg = lane >> 4;
  if (slot < 2048) {           // W1: K=128, N=128 (fp16)
    int ks = (slot >> 6) & 3, nt = slot >> 8;
    int k0 = ks * 32 + kg * 8, c = nt * 16 + j;
#pragma unroll
    for (int e = 0; e < 8; e++) W1F[(size_t)slot * 8 + e] = (f16)W1[(k0 + e) * 128 + c];
  } else if (slot < 4096) {    // W2: K=128, N=128 (fp16)
    int s2 = slot - 2048;
    int ks = (s2 >> 6) & 3, nt = s2 >> 8;
    int k0 = ks * 32 + kg * 8, c = nt * 16 + j;
#pragma unroll
    for (int e = 0; e < 8; e++) W2F[(size_t)s2 * 8 + e] = (f16)W2[(k0 + e) * 128 + c];
  } else if (slot < 8192) {    // Wc1: K=256, N=128 (bf16)
    int s3 = slot - 4096;
    int ks = (s3 >> 6) & 7, nt = s3 >> 9;
    int k0 = ks * 32 + kg * 8, c = nt * 16 + j;
#pragma unroll
    for (int e = 0; e < 8; e++) Wc1F[(size_t)s3 * 8 + e] = f2bf(Wc1[(k0 + e) * 128 + c]);
  } else if (slot < 9216) {    // Wc2: K=128, N=64 (bf16)
    int s4 = slot - 8192;
    int ks = (s4 >> 6) & 3, nt = s4 >> 8;
    int k0 = ks * 32 + kg * 8, c = nt * 16 + j;
#pragma unroll
    for (int e = 0; e < 8; e++) Wc2F[(size_t)s4 * 8 + e] = f2bf(Wc2[(k0 + e) * 64 + c]);
  } else if (slot < 10240) {   // Wc3: K=64, N=86 padded 128 (bf16)
    int s5 = slot - 9216;
    int ks = (s5 >> 6) & 1, nt = s5 >> 7;
    int k0 = ks * 32 + kg * 8, c = nt * 16 + j;
#pragma unroll
    for (int e = 0; e < 8; e++)
      Wc3F[(size_t)s5 * 8 + e] = f2bf((c < 86) ? Wc3[(k0 + e) * 86 + c] : 0.f);
  }
}

// single-block exclusive scan (4 elems/thread) + dinv = rsqrt(deg+1)
__global__ __launch_bounds__(1024) void scan_k(const int* __restrict__ deg, int* __restrict__ offs,
                                               float* __restrict__ dinv, int n) {
  __shared__ int wsum[16];
  __shared__ int wpre[16];
  __shared__ int run_s;
  int tid = threadIdx.x, lane = tid & 63, wid = tid >> 6;
  if (tid == 0) run_s = 0;
  __syncthreads();
  for (int base = 0; base < n; base += 4096) {
    int i4 = base + tid * 4;
    int4 v = make_int4(0, 0, 0, 0);
    if (i4 + 3 < n) v = *(const int4*)&deg[i4];
    else {
      if (i4 < n) v.x = deg[i4];
      if (i4 + 1 < n) v.y = deg[i4 + 1];
      if (i4 + 2 < n) v.z = deg[i4 + 2];
      if (i4 + 3 < n) v.w = deg[i4 + 3];
    }
    int tsum = v.x + v.y + v.z + v.w;
    int s = tsum;
#pragma unroll
    for (int d = 1; d < 64; d <<= 1) {
      int t = __shfl_up(s, d);
      if (lane >= d) s += t;
    }
    if (lane == 63) wsum[wid] = s;
    __syncthreads();
    if (tid == 0) {
      int acc = run_s;
#pragma unroll
      for (int w = 0; w < 16; w++) { wpre[w] = acc; acc += wsum[w]; }
      run_s = acc;
    }
    __syncthreads();
    int pre = wpre[wid] + (s - tsum);
    int4 o;
    o.x = pre; o.y = pre + v.x; o.z = o.y + v.y; o.w = o.z + v.z;
    float4 dv;
    dv.x = rsqrtf((float)v.x + 1.0f);
    dv.y = rsqrtf((float)v.y + 1.0f);
    dv.z = rsqrtf((float)v.z + 1.0f);
    dv.w = rsqrtf((float)v.w + 1.0f);
    if (i4 + 3 < n) {
      *(int4*)&offs[i4] = o;
      *(float4*)&dinv[i4] = dv;
    } else {
      if (i4 < n)     { offs[i4] = o.x;     dinv[i4] = dv.x; }
      if (i4 + 1 < n) { offs[i4 + 1] = o.y; dinv[i4 + 1] = dv.y; }
      if (i4 + 2 < n) { offs[i4 + 2] = o.z; dinv[i4 + 2] = dv.z; }
      if (i4 + 3 < n) { offs[i4 + 3] = o.w; dinv[i4 + 3] = dv.w; }
    }
    __syncthreads();
  }
  if (tid == 0) offs[n] = run_s;
}

// CSR placement, atomic-free: idx = offs[dst] + rank[e]; one packed u32 per edge.
__global__ __launch_bounds__(256) void fill_k(const int* __restrict__ ei, const int* __restrict__ offs,
                                              const int* __restrict__ rank, const float* __restrict__ dinv,
                                              u32* __restrict__ csrp, int E) {
  int e = blockIdx.x * 256 + threadIdx.x;
  if (e < E) {
    int s = ei[e], d = ei[E + e];
    int idx = offs[d] + rank[e];
    f16 hv = (f16)dinv[s];
    u32 pack = (u32)(u16)s | ((u32)(*(u16*)&hv) << 16);
    csrp[idx] = pack;
  }
}

// ---------------- fp16 MFMA node GEMM ----------------
// MODE 0: A fp32, no BN.  MODE 1: A fp16, BN(scale/shift from sums,gamma,beta)+ReLU fused into staging.

template<int MODE>
__global__ __launch_bounds__(256) void gemm_mfma_k(const void* __restrict__ Ain,
                                                   const float* __restrict__ sums,
                                                   const float* __restrict__ gamma,
                                                   const float* __restrict__ beta,
                                                   const f16* __restrict__ WF,
                                                   f16* __restrict__ outh, int n) {
  __shared__ f16 As[64 * 136];   // 272B row stride
  __shared__ float scsh[256];
  int tid = threadIdx.x;
  if (MODE == 1) {
    if (tid < 128) {
      const float inv_n = 1.0f / (float)N_NODES;
      float mean = sums[tid] * inv_n;
      float var = sums[128 + tid] * inv_n - mean * mean;
      float sc = gamma[tid] * rsqrtf(var + 1e-5f);
      scsh[tid] = sc;
      scsh[128 + tid] = beta[tid] - mean * sc;
    }
    __syncthreads();
  }
  int row0 = blockIdx.x * 64;
#pragma unroll
  for (int it = 0; it < 8; it++) {
    int idx = it * 256 + tid;          // 0..2047
    int r = idx >> 5, c4 = (idx & 31) * 4;
    int gr = row0 + r; if (gr >= n) gr = n - 1;
    float4 v;
    if (MODE == 0) {
      v = *(const float4*)&((const float*)Ain)[(size_t)gr * 128 + c4];
    } else {
      h4 hv4 = *(const h4*)&((const f16*)Ain)[(size_t)gr * 128 + c4];
      v.x = (float)hv4[0]; v.y = (float)hv4[1]; v.z = (float)hv4[2]; v.w = (float)hv4[3];
      v.x = fmaxf(v.x * scsh[c4 + 0] + scsh[128 + c4 + 0], 0.f);
      v.y = fmaxf(v.y * scsh[c4 + 1] + scsh[128 + c4 + 1], 0.f);
      v.z = fmaxf(v.z * scsh[c4 + 2] + scsh[128 + c4 + 2], 0.f);
      v.w = fmaxf(v.w * scsh[c4 + 3] + scsh[128 + c4 + 3], 0.f);
    }
    h4 hv; hv[0] = (f16)v.x; hv[1] = (f16)v.y; hv[2] = (f16)v.z; hv[3] = (f16)v.w;
    *(h4*)&As[r * 136 + c4] = hv;
  }
  __syncthreads();
  int w = tid >> 6, lane = tid & 63, li = lane & 15, kg = lane >> 4;
  f32x4 acc[4][2];
#pragma unroll
  for (int mt = 0; mt < 4; mt++)
#pragma unroll
    for (int ntl = 0; ntl < 2; ntl++)
#pragma unroll
      for (int q = 0; q < 4; q++) acc[mt][ntl][q] = 0.f;
#pragma unroll
  for (int ks = 0; ks < 4; ks++) {
    h8 a[4];
#pragma unroll
    for (int mt = 0; mt < 4; mt++)
      a[mt] = *(const h8*)&As[(mt * 16 + li) * 136 + kg * 8 + ks * 32];
#pragma unroll
    for (int ntl = 0; ntl < 2; ntl++) {
      int nt = 2 * w + ntl;
      h8 b = *(const h8*)&WF[((size_t)(nt * 4 + ks) * 64 + lane) * 8];
#pragma unroll
      for (int mt = 0; mt < 4; mt++)
        acc[mt][ntl] = __builtin_amdgcn_mfma_f32_16x16x32_f16(a[mt], b, acc[mt][ntl], 0, 0, 0);
    }
  }
  __syncthreads();
#pragma unroll
  for (int mt = 0; mt < 4; mt++)
#pragma unroll
    for (int ntl = 0; ntl < 2; ntl++)
#pragma unroll
      for (int r = 0; r < 4; r++)
        As[(mt * 16 + kg * 4 + r) * 136 + (2 * w + ntl) * 16 + li] = (f16)acc[mt][ntl][r];
  __syncthreads();
#pragma unroll
  for (int it = 0; it < 4; it++) {
    int idx = it * 256 + tid;          // 0..1023
    int r = idx >> 4, c8 = (idx & 15) * 8;
    int gr = row0 + r;
    if (gr < n) *(h8*)&outh[(size_t)gr * 128 + c8] = *(const h8*)&As[r * 136 + c8];
  }
}

// ---------------- CSR gather aggregation ----------------
// One wave per node; two half-waves each handle one edge per step (lane reads u64 = 4 fp16).
// 4x unroll -> 8 edges in flight per wave. shfl_xor(32) merges half-waves at the end.

__global__ __launch_bounds__(256) void agg_h_k(const f16* __restrict__ th, const float* __restrict__ dinv,
                                               const int* __restrict__ offs, const u32* __restrict__ csrp,
                                               const float* __restrict__ bias, f16* __restrict__ outh, int n) {
  int tid = threadIdx.x;
  int w = tid >> 6, lane = tid & 63;
  int half = lane >> 5, sl = lane & 31;
  int node = blockIdx.x * 4 + w;
  if (node >= n) return;
  const u64* hu8 = (const u64*)th;
  float di = dinv[node];
  int e0 = offs[node], e1 = offs[node + 1];
  union C8 { u64 u; f16 h[4]; };
  float a0[4] = {0.f, 0.f, 0.f, 0.f};
  float a1[4] = {0.f, 0.f, 0.f, 0.f};
  float a2[4] = {0.f, 0.f, 0.f, 0.f};
  float a3[4] = {0.f, 0.f, 0.f, 0.f};
  int e = e0;
  for (; e + 8 <= e1; e += 8) {
    u32 p0 = csrp[e + half];
    u32 p1 = csrp[e + 2 + half];
    u32 p2 = csrp[e + 4 + half];
    u32 p3 = csrp[e + 6 + half];
    C8 v0, v1, v2, v3;
    v0.u = hu8[(size_t)(p0 & 0xFFFF) * 32 + sl];
    v1.u = hu8[(size_t)(p1 & 0xFFFF) * 32 + sl];
    v2.u = hu8[(size_t)(p2 & 0xFFFF) * 32 + sl];
    v3.u = hu8[(size_t)(p3 & 0xFFFF) * 32 + sl];
    float c0 = bits2f(p0 >> 16), c1 = bits2f(p1 >> 16);
    float c2 = bits2f(p2 >> 16), c3 = bits2f(p3 >> 16);
#pragma unroll
    for (int j = 0; j < 4; j++) {
      a0[j] += c0 * (float)v0.h[j];
      a1[j] += c1 * (float)v1.h[j];
      a2[j] += c2 * (float)v2.h[j];
      a3[j] += c3 * (float)v3.h[j];
    }
  }
  for (; e < e1; e += 2) {
    int ee = e + half;
    bool valid = ee < e1;
    u32 p0 = csrp[valid ? ee : e];
    float c0 = valid ? bits2f(p0 >> 16) : 0.f;
    C8 v0; v0.u = hu8[(size_t)(p0 & 0xFFFF) * 32 + sl];
#pragma unroll
    for (int j = 0; j < 4; j++) a0[j] += c0 * (float)v0.h[j];
  }
  float s[4];
#pragma unroll
  for (int j = 0; j < 4; j++) {
    s[j] = (a0[j] + a1[j]) + (a2[j] + a3[j]);
    s[j] += __shfl_xor(s[j], 32);
  }
  if (half == 0) {
    C8 vs; vs.u = hu8[(size_t)node * 32 + sl];
    float4 b4 = *(const float4*)&bias[sl * 4];
    float sc = di * di;
    C8 o;
    o.h[0] = (f16)(di * s[0] + sc * (float)vs.h[0] + b4.x);
    o.h[1] = (f16)(di * s[1] + sc * (float)vs.h[1] + b4.y);
    o.h[2] = (f16)(di * s[2] + sc * (float)vs.h[2] + b4.z);
    o.h[3] = (f16)(di * s[3] + sc * (float)vs.h[3] + b4.w);
    ((u64*)outh)[(size_t)node * 32 + sl] = o.u;
  }
}

// ---------------- BN stats over fp16 h (sum, sumsq per column) ----------------

__global__ __launch_bounds__(256) void bn_stats_h_k(const f16* __restrict__ h, float* __restrict__ sums, int n) {
  int tid = threadIdx.x;
  int c = tid & 63, rg = tid >> 6;       // c: column pair, rg: row group 0..3
  const u32* hu = (const u32*)h;
  union CV { u32 u; f16 h[2]; };
  float sx = 0.f, sy = 0.f, qx = 0.f, qy = 0.f;
  for (int r = blockIdx.x * 4 + rg; r < n; r += gridDim.x * 4) {
    CV v; v.u = hu[(size_t)r * 64 + c];
    float x = (float)v.h[0], y = (float)v.h[1];
    sx += x; qx += x * x;
    sy += y; qy += y * y;
  }
  __shared__ float rsum[4][128];
  __shared__ float rsq[4][128];
  rsum[rg][c * 2] = sx; rsum[rg][c * 2 + 1] = sy;
  rsq[rg][c * 2] = qx;  rsq[rg][c * 2 + 1] = qy;
  __syncthreads();
  if (tid < 128) {
    float a = (rsum[0][tid] + rsum[1][tid]) + (rsum[2][tid] + rsum[3][tid]);
    float b = (rsq[0][tid] + rsq[1][tid]) + (rsq[2][tid] + rsq[3][tid]);
    atomicAdd(&sums[tid], a);
    atomicAdd(&sums[128 + tid], b);
  }
}

// ---------------- layer-2 BN+ReLU (scale/shift computed in-block), emit bf16 ----------------

__global__ __launch_bounds__(256) void bn_apply_bf16_k(const f16* __restrict__ h, const float* __restrict__ sums,
                                                       const float* __restrict__ gamma, const float* __restrict__ beta,
                                                       u16* __restrict__ hb) {
  __shared__ float scsh[256];
  int tid = threadIdx.x;
  if (tid < 128) {
    const float inv_n = 1.0f / (float)N_NODES;
    float mean = sums[tid] * inv_n;
    float var = sums[128 + tid] * inv_n - mean * mean;
    float sc = gamma[tid] * rsqrtf(var + 1e-5f);
    scsh[tid] = sc;
    scsh[128 + tid] = beta[tid] - mean * sc;
  }
  __syncthreads();
  int idx = blockIdx.x * 256 + tid;
  int c0 = (idx & 31) * 4;
  h4 v4 = *(const h4*)&h[(size_t)idx * 4];
  ushort4 o;
  o.x = f2bf(fmaxf((float)v4[0] * scsh[c0 + 0] + scsh[128 + c0 + 0], 0.f));
  o.y = f2bf(fmaxf((float)v4[1] * scsh[c0 + 1] + scsh[128 + c0 + 1], 0.f));
  o.z = f2bf(fmaxf((float)v4[2] * scsh[c0 + 2] + scsh[128 + c0 + 2], 0.f));
  o.w = f2bf(fmaxf((float)v4[3] * scsh[c0 + 3] + scsh[128 + c0 + 3], 0.f));
  *(ushort4*)&hb[(size_t)idx * 4] = o;
}

// ---------------- fused pair classifier (bf16 MFMA) ----------------
// 64 pairs/block, 4 waves. comb[64x256]bf16 (528B rows), z1[64x128]bf16 (272B),
// z2[64x64]bf16 (144B, aliases comb). Weights pre-packed frag-linear.

#define SM_Z1 33792
#define SM_TOT (33792 + 17408)

__global__ __launch_bounds__(256) void classifier_k(const u16* __restrict__ hbf, const int* __restrict__ pairs,
    const u16* __restrict__ Wc1F, const float* __restrict__ bc1,
    const u16* __restrict__ Wc2F, const float* __restrict__ bc2,
    const u16* __restrict__ Wc3F, const float* __restrict__ bc3,
    float* __restrict__ out) {
  __shared__ __align__(16) char smem[SM_TOT];
  __shared__ int nodes[128];
  int tid = threadIdx.x;
  int p0 = blockIdx.x * 64;
  if (tid < 128) {
    int gi = p0 * 2 + tid;
    nodes[tid] = (gi < NPAIRS * 2) ? pairs[gi] : 0;
  }
  __syncthreads();
  int w = tid >> 6, lane = tid & 63;
  int li = lane & 15, kg = lane >> 4;

  // gather 128 node halves -> comb (row-major bf16, 528B pair stride)
  {
    unsigned int* cmb = (unsigned int*)smem;
    for (int s = w * 32; s < w * 32 + 32; s++) {
      int nd = nodes[s];
      unsigned int v = ((const unsigned int*)hbf)[(size_t)nd * 64 + lane];
      cmb[(s >> 1) * 132 + (s & 1) * 64 + lane] = v;
    }
  }
  __syncthreads();

  // phase 1: z1 = relu(comb @ Wc1 + bc1)   M=64 K=256 N=128; wave -> N-tiles {2w,2w+1}
  {
    f32x4 acc[4][2];
#pragma unroll
    for (int ntl = 0; ntl < 2; ntl++) {
      float b = bc1[(2 * w + ntl) * 16 + li];
#pragma unroll
      for (int mt = 0; mt < 4; mt++)
#pragma unroll
        for (int q = 0; q < 4; q++) acc[mt][ntl][q] = b;
    }
    for (int ks = 0; ks < 8; ks++) {
      short8v a[4];
#pragma unroll
      for (int mt = 0; mt < 4; mt++)
        a[mt] = *(const short8v*)(smem + (mt * 16 + li) * 528 + kg * 16 + ks * 64);
#pragma unroll
      for (int ntl = 0; ntl < 2; ntl++) {
        int nt = 2 * w + ntl;
        short8v b = *(const short8v*)(Wc1F + ((size_t)(nt * 8 + ks) * 64 + lane) * 8);
#pragma unroll
        for (int mt = 0; mt < 4; mt++)
          acc[mt][ntl] = __builtin_amdgcn_mfma_f32_16x16x32_bf16(a[mt], b, acc[mt][ntl], 0, 0, 0);
      }
    }
#pragma unroll
    for (int mt = 0; mt < 4; mt++)
#pragma unroll
      for (int ntl = 0; ntl < 2; ntl++)
#pragma unroll
        for (int r = 0; r < 4; r++) {
          int row = mt * 16 + kg * 4 + r;
          int col = (2 * w + ntl) * 16 + li;
          *(u16*)(smem + SM_Z1 + row * 272 + col * 2) = f2bf(fmaxf(acc[mt][ntl][r], 0.f));
        }
  }
  __syncthreads();

  // phase 2: z2 = relu(z1 @ Wc2 + bc2)   M=64 K=128 N=64; wave -> N-tile w
  {
    f32x4 acc[4];
    float b = bc2[w * 16 + li];
#pragma unroll
    for (int mt = 0; mt < 4; mt++)
#pragma unroll
      for (int q = 0; q < 4; q++) acc[mt][q] = b;
    for (int ks = 0; ks < 4; ks++) {
      short8v a[4];
#pragma unroll
      for (int mt = 0; mt < 4; mt++)
        a[mt] = *(const short8v*)(smem + SM_Z1 + (mt * 16 + li) * 272 + kg * 16 + ks * 64);
      short8v bf = *(const short8v*)(Wc2F + ((size_t)(w * 4 + ks) * 64 + lane) * 8);
#pragma unroll
      for (int mt = 0; mt < 4; mt++)
        acc[mt] = __builtin_amdgcn_mfma_f32_16x16x32_bf16(a[mt], bf, acc[mt], 0, 0, 0);
    }
#pragma unroll
    for (int mt = 0; mt < 4; mt++)
#pragma unroll
      for (int r = 0; r < 4; r++) {
        int row = mt * 16 + kg * 4 + r;
        int col = w * 16 + li;
        *(u16*)(smem + row * 144 + col * 2) = f2bf(fmaxf(acc[mt][r], 0.f));
      }
  }
  __syncthreads();

  // phase 3: out = z2 @ Wc3 + bc3   M=64 K=64 N=86 (padded 128); wave -> N-tiles {2w,2w+1}
  {
    f32x4 acc[4][2];
#pragma unroll
    for (int ntl = 0; ntl < 2; ntl++) {
      int col = (2 * w + ntl) * 16 + li;
      float b = (col < 86) ? bc3[col] : 0.f;
#pragma unroll
      for (int mt = 0; mt < 4; mt++)
#pragma unroll
        for (int q = 0; q < 4; q++) acc[mt][ntl][q] = b;
    }
    for (int ks = 0; ks < 2; ks++) {
      short8v a[4];
#pragma unroll
      for (int mt = 0; mt < 4; mt++)
        a[mt] = *(const short8v*)(smem + (mt * 16 + li) * 144 + kg * 16 + ks * 64);
#pragma unroll
      for (int ntl = 0; ntl < 2; ntl++) {
        int nt = 2 * w + ntl;
        short8v bf = *(const short8v*)(Wc3F + ((size_t)(nt * 2 + ks) * 64 + lane) * 8);
#pragma unroll
        for (int mt = 0; mt < 4; mt++)
          acc[mt][ntl] = __builtin_amdgcn_mfma_f32_16x16x32_bf16(a[mt], bf, acc[mt][ntl], 0, 0, 0);
      }
    }
#pragma unroll
    for (int mt = 0; mt < 4; mt++)
#pragma unroll
      for (int ntl = 0; ntl < 2; ntl++) {
        int col = (2 * w + ntl) * 16 + li;
        if (col < 86) {
#pragma unroll
          for (int r = 0; r < 4; r++) {
            int row = p0 + mt * 16 + kg * 4 + r;
            if (row < NPAIRS) out[(size_t)row * 86 + col] = acc[mt][ntl][r];
          }
        }
      }
  }
}

// ---------------- launch ----------------

extern "C" void kernel_launch(void* const* d_in, const int* in_sizes, int n_in,
                              void* d_out, int out_size, void* d_ws, size_t ws_size,
                              hipStream_t stream) {
  (void)in_sizes; (void)n_in; (void)out_size; (void)ws_size;
  const float* x   = (const float*)d_in[0];
  const int*   ei  = (const int*)d_in[1];
  const int* pairs = (const int*)d_in[2];
  const float* W1  = (const float*)d_in[3];
  const float* b1  = (const float*)d_in[4];
  const float* g1  = (const float*)d_in[5];
  const float* be1 = (const float*)d_in[6];
  const float* W2  = (const float*)d_in[7];
  const float* b2  = (const float*)d_in[8];
  const float* g2  = (const float*)d_in[9];
  const float* be2 = (const float*)d_in[10];
  const float* Wc1 = (const float*)d_in[11];
  const float* bc1 = (const float*)d_in[12];
  const float* Wc2 = (const float*)d_in[13];
  const float* bc2 = (const float*)d_in[14];
  const float* Wc3 = (const float*)d_in[15];
  const float* bc3 = (const float*)d_in[16];
  float* out = (float*)d_out;

  size_t off = 0;
  auto alloc = [&](size_t bytes) -> char* {
    char* p = (char*)d_ws + off;
    off += (bytes + 255) & ~(size_t)255;
    return p;
  };
  int* deg      = (int*)alloc(N_NODES * 4);
  float* sums1  = (float*)alloc(256 * 4);
  float* sums2  = (float*)alloc(256 * 4);
  size_t zero_span = off;
  int* offs     = (int*)alloc((N_NODES + 1) * 4);
  int* rank     = (int*)alloc(N_EDGES * 4);
  u32* csrp     = (u32*)alloc(N_EDGES * 4);
  float* dinv   = (float*)alloc(N_NODES * 4);
  f16* W1F      = (f16*)alloc(2048 * 8 * 2);
  f16* W2F      = (f16*)alloc(2048 * 8 * 2);
  u16* Wc1F     = (u16*)alloc(4096 * 8 * 2);
  u16* Wc2F     = (u16*)alloc(1024 * 8 * 2);
  u16* Wc3F     = (u16*)alloc(1024 * 8 * 2);
  f16* th       = (f16*)alloc((size_t)N_NODES * 128 * 2);
  f16* hA       = (f16*)alloc((size_t)N_NODES * 128 * 2);
  u16* hbf      = (u16*)th;   // aliases th (t2 dead when written)

  hipMemsetAsync(d_ws, 0, zero_span, stream);
  pre_k<<<N_EDGES / 256 + 40, 256, 0, stream>>>(ei, deg, rank, W1, W2, Wc1, Wc2, Wc3,
                                                W1F, W2F, Wc1F, Wc2F, Wc3F);
  scan_k<<<1, 1024, 0, stream>>>(deg, offs, dinv, N_NODES);
  fill_k<<<N_EDGES / 256, 256, 0, stream>>>(ei, offs, rank, dinv, csrp, N_EDGES);

  // layer 1: t1 = x @ W1; agg; stats1
  gemm_mfma_k<0><<<(N_NODES + 63) / 64, 256, 0, stream>>>(x, nullptr, nullptr, nullptr, W1F, th, N_NODES);
  agg_h_k<<<(N_NODES + 3) / 4, 256, 0, stream>>>(th, dinv, offs, csrp, b1, hA, N_NODES);
  bn_stats_h_k<<<256, 256, 0, stream>>>(hA, sums1, N_NODES);

  // layer 2: t2 = bnrelu(h1) @ W2 (BN from sums1 fused); agg; stats2
  gemm_mfma_k<1><<<(N_NODES + 63) / 64, 256, 0, stream>>>(hA, sums1, g1, be1, W2F, th, N_NODES);
  agg_h_k<<<(N_NODES + 3) / 4, 256, 0, stream>>>(th, dinv, offs, csrp, b2, hA, N_NODES);
  bn_stats_h_k<<<256, 256, 0, stream>>>(hA, sums2, N_NODES);

  // BN2 + ReLU -> bf16 classifier input
  bn_apply_bf16_k<<<(N_NODES * 128) / 1024, 256, 0, stream>>>(hA, sums2, g2, be2, hbf);

  // classifier
  classifier_k<<<(NPAIRS + 63) / 64, 256, 0, stream>>>(hbf, pairs, Wc1F, bc1, Wc2F, bc2, Wc3F, bc3, out);
}

// Round 7
// 333.495 us; speedup vs baseline: 2.7667x; 1.0069x over previous
//
#include <hip/hip_runtime.h>
#include <cstdint>

#define N_NODES 50000
#define N_EDGES 800000
#define NPAIRS  100000

typedef unsigned short u16;
typedef unsigned int u32;
typedef unsigned long long u64;
typedef _Float16 f16;
typedef short short8v __attribute__((ext_vector_type(8)));
typedef _Float16 h8 __attribute__((ext_vector_type(8)));
typedef _Float16 h4 __attribute__((ext_vector_type(4)));
typedef float f32x4 __attribute__((ext_vector_type(4)));

static __device__ __forceinline__ u16 f2bf(float f) {
  unsigned int u = __float_as_uint(f);
  u += 0x7FFF + ((u >> 16) & 1);
  return (u16)(u >> 16);
}

static __device__ __forceinline__ float bits2f(u32 hi) {
  union { u16 b; f16 h; } x;
  x.b = (u16)hi;
  return (float)x.h;
}

// ---------------- weight packing (runs first; tiny) ----------------

__global__ __launch_bounds__(256) void wpack_k(const float* __restrict__ W1, const float* __restrict__ W2,
                                               const float* __restrict__ Wc1, const float* __restrict__ Wc2,
                                               const float* __restrict__ Wc3,
                                               f16* __restrict__ W1F, f16* __restrict__ W2F,
                                               u16* __restrict__ Wc1F, u16* __restrict__ Wc2F, u16* __restrict__ Wc3F) {
  int slot = blockIdx.x * 256 + threadIdx.x;
  int lane = slot & 63, j = lane & 15, kg = lane >> 4;
  if (slot < 2048) {           // W1: K=128, N=128 (fp16)
    int ks = (slot >> 6) & 3, nt = slot >> 8;
    int k0 = ks * 32 + kg * 8, c = nt * 16 + j;
#pragma unroll
    for (int e = 0; e < 8; e++) W1F[(size_t)slot * 8 + e] = (f16)W1[(k0 + e) * 128 + c];
  } else if (slot < 4096) {    // W2: K=128, N=128 (fp16)
    int s2 = slot - 2048;
    int ks = (s2 >> 6) & 3, nt = s2 >> 8;
    int k0 = ks * 32 + kg * 8, c = nt * 16 + j;
#pragma unroll
    for (int e = 0; e < 8; e++) W2F[(size_t)s2 * 8 + e] = (f16)W2[(k0 + e) * 128 + c];
  } else if (slot < 8192) {    // Wc1: K=256, N=128 (bf16)
    int s3 = slot - 4096;
    int ks = (s3 >> 6) & 7, nt = s3 >> 9;
    int k0 = ks * 32 + kg * 8, c = nt * 16 + j;
#pragma unroll
    for (int e = 0; e < 8; e++) Wc1F[(size_t)s3 * 8 + e] = f2bf(Wc1[(k0 + e) * 128 + c]);
  } else if (slot < 9216) {    // Wc2: K=128, N=64 (bf16)
    int s4 = slot - 8192;
    int ks = (s4 >> 6) & 3, nt = s4 >> 8;
    int k0 = ks * 32 + kg * 8, c = nt * 16 + j;
#pragma unroll
    for (int e = 0; e < 8; e++) Wc2F[(size_t)s4 * 8 + e] = f2bf(Wc2[(k0 + e) * 64 + c]);
  } else if (slot < 10240) {   // Wc3: K=64, N=86 padded 128 (bf16)
    int s5 = slot - 9216;
    int ks = (s5 >> 6) & 1, nt = s5 >> 7;
    int k0 = ks * 32 + kg * 8, c = nt * 16 + j;
#pragma unroll
    for (int e = 0; e < 8; e++)
      Wc3F[(size_t)s5 * 8 + e] = f2bf((c < 86) ? Wc3[(k0 + e) * 86 + c] : 0.f);
  }
}

// ---------------- fp16 MFMA node GEMM body ----------------
// MODE 0: A fp32, no BN.  MODE 1: A fp16, BN(from sums,gamma,beta)+ReLU fused into staging.

template<int MODE>
static __device__ __forceinline__ void gemm_body(const void* __restrict__ Ain,
                                                 const float* __restrict__ sums,
                                                 const float* __restrict__ gamma,
                                                 const float* __restrict__ beta,
                                                 const f16* __restrict__ WF,
                                                 f16* __restrict__ outh, int n, int row0,
                                                 f16* As, float* scsh) {
  int tid = threadIdx.x;
  if constexpr (MODE == 1) {
    if (tid < 128) {
      const float inv_n = 1.0f / (float)N_NODES;
      float mean = sums[tid] * inv_n;
      float var = sums[128 + tid] * inv_n - mean * mean;
      float sc = gamma[tid] * rsqrtf(var + 1e-5f);
      scsh[tid] = sc;
      scsh[128 + tid] = beta[tid] - mean * sc;
    }
    __syncthreads();
  }
#pragma unroll
  for (int it = 0; it < 8; it++) {
    int idx = it * 256 + tid;          // 0..2047
    int r = idx >> 5, c4 = (idx & 31) * 4;
    int gr = row0 + r; if (gr >= n) gr = n - 1;
    float4 v;
    if constexpr (MODE == 0) {
      v = *(const float4*)&((const float*)Ain)[(size_t)gr * 128 + c4];
    } else {
      h4 hv4 = *(const h4*)&((const f16*)Ain)[(size_t)gr * 128 + c4];
      v.x = (float)hv4[0]; v.y = (float)hv4[1]; v.z = (float)hv4[2]; v.w = (float)hv4[3];
      v.x = fmaxf(v.x * scsh[c4 + 0] + scsh[128 + c4 + 0], 0.f);
      v.y = fmaxf(v.y * scsh[c4 + 1] + scsh[128 + c4 + 1], 0.f);
      v.z = fmaxf(v.z * scsh[c4 + 2] + scsh[128 + c4 + 2], 0.f);
      v.w = fmaxf(v.w * scsh[c4 + 3] + scsh[128 + c4 + 3], 0.f);
    }
    h4 hv; hv[0] = (f16)v.x; hv[1] = (f16)v.y; hv[2] = (f16)v.z; hv[3] = (f16)v.w;
    *(h4*)&As[r * 136 + c4] = hv;
  }
  __syncthreads();
  int w = tid >> 6, lane = tid & 63, li = lane & 15, kg = lane >> 4;
  f32x4 acc[4][2];
#pragma unroll
  for (int mt = 0; mt < 4; mt++)
#pragma unroll
    for (int ntl = 0; ntl < 2; ntl++)
#pragma unroll
      for (int q = 0; q < 4; q++) acc[mt][ntl][q] = 0.f;
#pragma unroll
  for (int ks = 0; ks < 4; ks++) {
    h8 a[4];
#pragma unroll
    for (int mt = 0; mt < 4; mt++)
      a[mt] = *(const h8*)&As[(mt * 16 + li) * 136 + kg * 8 + ks * 32];
#pragma unroll
    for (int ntl = 0; ntl < 2; ntl++) {
      int nt = 2 * w + ntl;
      h8 b = *(const h8*)&WF[((size_t)(nt * 4 + ks) * 64 + lane) * 8];
#pragma unroll
      for (int mt = 0; mt < 4; mt++)
        acc[mt][ntl] = __builtin_amdgcn_mfma_f32_16x16x32_f16(a[mt], b, acc[mt][ntl], 0, 0, 0);
    }
  }
  __syncthreads();
#pragma unroll
  for (int mt = 0; mt < 4; mt++)
#pragma unroll
    for (int ntl = 0; ntl < 2; ntl++)
#pragma unroll
      for (int r = 0; r < 4; r++)
        As[(mt * 16 + kg * 4 + r) * 136 + (2 * w + ntl) * 16 + li] = (f16)acc[mt][ntl][r];
  __syncthreads();
#pragma unroll
  for (int it = 0; it < 4; it++) {
    int idx = it * 256 + tid;          // 0..1023
    int r = idx >> 4, c8 = (idx & 15) * 8;
    int gr = row0 + r;
    if (gr < n) *(h8*)&outh[(size_t)gr * 128 + c8] = *(const h8*)&As[r * 136 + c8];
  }
}

// ---------------- fused: edge-rank count (blocks 0..3124) + gemm1 (rest) ----------------

__global__ __launch_bounds__(256) void fused1_k(const int* __restrict__ ei, int* __restrict__ deg,
                                                int* __restrict__ rank,
                                                const float* __restrict__ x, const f16* __restrict__ W1F,
                                                f16* __restrict__ th, int n) {
  __shared__ f16 As[64 * 136];
  int b = blockIdx.x;
  if (b < N_EDGES / 256) {
    int e = b * 256 + threadIdx.x;
    rank[e] = atomicAdd(&deg[ei[N_EDGES + e]], 1);
    return;
  }
  gemm_body<0>(x, nullptr, nullptr, nullptr, W1F, th, n, (b - N_EDGES / 256) * 64, As, nullptr);
}

// ---------------- standalone gemm2 (BN1 fused) ----------------

__global__ __launch_bounds__(256) void gemm2_k(const f16* __restrict__ Ain, const float* __restrict__ sums,
                                               const float* __restrict__ gamma, const float* __restrict__ beta,
                                               const f16* __restrict__ W2F, f16* __restrict__ th, int n) {
  __shared__ f16 As[64 * 136];
  __shared__ float scsh[256];
  gemm_body<1>(Ain, sums, gamma, beta, W2F, th, n, blockIdx.x * 64, As, scsh);
}

// single-block exclusive scan (8 elems/thread) + dinv = rsqrt(deg+1)
__global__ __launch_bounds__(1024) void scan_k(const int* __restrict__ deg, int* __restrict__ offs,
                                               float* __restrict__ dinv, int n) {
  __shared__ int wsum[16];
  __shared__ int wpre[16];
  __shared__ int run_s;
  int tid = threadIdx.x, lane = tid & 63, wid = tid >> 6;
  if (tid == 0) run_s = 0;
  __syncthreads();
  for (int base = 0; base < n; base += 8192) {
    int i8 = base + tid * 8;
    int v[8];
    if (i8 + 7 < n) {
      *(int4*)&v[0] = *(const int4*)&deg[i8];
      *(int4*)&v[4] = *(const int4*)&deg[i8 + 4];
    } else {
#pragma unroll
      for (int j = 0; j < 8; j++) v[j] = (i8 + j < n) ? deg[i8 + j] : 0;
    }
    int tsum = 0;
#pragma unroll
    for (int j = 0; j < 8; j++) tsum += v[j];
    int s = tsum;
#pragma unroll
    for (int d = 1; d < 64; d <<= 1) {
      int t = __shfl_up(s, d);
      if (lane >= d) s += t;
    }
    if (lane == 63) wsum[wid] = s;
    __syncthreads();
    if (tid == 0) {
      int acc = run_s;
#pragma unroll
      for (int w = 0; w < 16; w++) { wpre[w] = acc; acc += wsum[w]; }
      run_s = acc;
    }
    __syncthreads();
    int pre = wpre[wid] + (s - tsum);
    int o[8];
    o[0] = pre;
#pragma unroll
    for (int j = 1; j < 8; j++) o[j] = o[j - 1] + v[j - 1];
    float dv[8];
#pragma unroll
    for (int j = 0; j < 8; j++) dv[j] = rsqrtf((float)v[j] + 1.0f);
    if (i8 + 7 < n) {
      *(int4*)&offs[i8] = *(int4*)&o[0];
      *(int4*)&offs[i8 + 4] = *(int4*)&o[4];
      *(float4*)&dinv[i8] = *(float4*)&dv[0];
      *(float4*)&dinv[i8 + 4] = *(float4*)&dv[4];
    } else {
#pragma unroll
      for (int j = 0; j < 8; j++)
        if (i8 + j < n) { offs[i8 + j] = o[j]; dinv[i8 + j] = dv[j]; }
    }
    __syncthreads();
  }
  if (tid == 0) offs[n] = run_s;
}

// CSR placement, atomic-free: idx = offs[dst] + rank[e]; one packed u32 per edge.
__global__ __launch_bounds__(256) void fill_k(const int* __restrict__ ei, const int* __restrict__ offs,
                                              const int* __restrict__ rank, const float* __restrict__ dinv,
                                              u32* __restrict__ csrp, int E) {
  int e = blockIdx.x * 256 + threadIdx.x;
  if (e < E) {
    int s = ei[e], d = ei[E + e];
    int idx = offs[d] + rank[e];
    f16 hv = (f16)dinv[s];
    u32 pack = (u32)(u16)s | ((u32)(*(u16*)&hv) << 16);
    csrp[idx] = pack;
  }
}

// ---------------- CSR gather aggregation ----------------
// One wave per node; two half-waves each handle one edge per step (lane reads u64 = 4 fp16).

__global__ __launch_bounds__(256) void agg_h_k(const f16* __restrict__ th, const float* __restrict__ dinv,
                                               const int* __restrict__ offs, const u32* __restrict__ csrp,
                                               const float* __restrict__ bias, f16* __restrict__ outh, int n) {
  int tid = threadIdx.x;
  int w = tid >> 6, lane = tid & 63;
  int half = lane >> 5, sl = lane & 31;
  int node = blockIdx.x * 4 + w;
  if (node >= n) return;
  const u64* hu8 = (const u64*)th;
  float di = dinv[node];
  int e0 = offs[node], e1 = offs[node + 1];
  union C8 { u64 u; f16 h[4]; };
  float a0[4] = {0.f, 0.f, 0.f, 0.f};
  float a1[4] = {0.f, 0.f, 0.f, 0.f};
  float a2[4] = {0.f, 0.f, 0.f, 0.f};
  float a3[4] = {0.f, 0.f, 0.f, 0.f};
  int e = e0;
  for (; e + 8 <= e1; e += 8) {
    u32 p0 = csrp[e + half];
    u32 p1 = csrp[e + 2 + half];
    u32 p2 = csrp[e + 4 + half];
    u32 p3 = csrp[e + 6 + half];
    C8 v0, v1, v2, v3;
    v0.u = hu8[(size_t)(p0 & 0xFFFF) * 32 + sl];
    v1.u = hu8[(size_t)(p1 & 0xFFFF) * 32 + sl];
    v2.u = hu8[(size_t)(p2 & 0xFFFF) * 32 + sl];
    v3.u = hu8[(size_t)(p3 & 0xFFFF) * 32 + sl];
    float c0 = bits2f(p0 >> 16), c1 = bits2f(p1 >> 16);
    float c2 = bits2f(p2 >> 16), c3 = bits2f(p3 >> 16);
#pragma unroll
    for (int j = 0; j < 4; j++) {
      a0[j] += c0 * (float)v0.h[j];
      a1[j] += c1 * (float)v1.h[j];
      a2[j] += c2 * (float)v2.h[j];
      a3[j] += c3 * (float)v3.h[j];
    }
  }
  for (; e < e1; e += 2) {
    int ee = e + half;
    bool valid = ee < e1;
    u32 p0 = csrp[valid ? ee : e];
    float c0 = valid ? bits2f(p0 >> 16) : 0.f;
    C8 v0; v0.u = hu8[(size_t)(p0 & 0xFFFF) * 32 + sl];
#pragma unroll
    for (int j = 0; j < 4; j++) a0[j] += c0 * (float)v0.h[j];
  }
  float s[4];
#pragma unroll
  for (int j = 0; j < 4; j++) {
    s[j] = (a0[j] + a1[j]) + (a2[j] + a3[j]);
    s[j] += __shfl_xor(s[j], 32);
  }
  if (half == 0) {
    C8 vs; vs.u = hu8[(size_t)node * 32 + sl];
    float4 b4 = *(const float4*)&bias[sl * 4];
    float sc = di * di;
    C8 o;
    o.h[0] = (f16)(di * s[0] + sc * (float)vs.h[0] + b4.x);
    o.h[1] = (f16)(di * s[1] + sc * (float)vs.h[1] + b4.y);
    o.h[2] = (f16)(di * s[2] + sc * (float)vs.h[2] + b4.z);
    o.h[3] = (f16)(di * s[3] + sc * (float)vs.h[3] + b4.w);
    ((u64*)outh)[(size_t)node * 32 + sl] = o.u;
  }
}

// ---------------- BN stats over fp16 h (sum, sumsq per column) ----------------

__global__ __launch_bounds__(256) void bn_stats_h_k(const f16* __restrict__ h, float* __restrict__ sums, int n) {
  int tid = threadIdx.x;
  int c = tid & 63, rg = tid >> 6;       // c: column pair, rg: row group 0..3
  const u32* hu = (const u32*)h;
  union CV { u32 u; f16 h[2]; };
  float sx = 0.f, sy = 0.f, qx = 0.f, qy = 0.f;
  for (int r = blockIdx.x * 4 + rg; r < n; r += gridDim.x * 4) {
    CV v; v.u = hu[(size_t)r * 64 + c];
    float x = (float)v.h[0], y = (float)v.h[1];
    sx += x; qx += x * x;
    sy += y; qy += y * y;
  }
  __shared__ float rsum[4][128];
  __shared__ float rsq[4][128];
  rsum[rg][c * 2] = sx; rsum[rg][c * 2 + 1] = sy;
  rsq[rg][c * 2] = qx;  rsq[rg][c * 2 + 1] = qy;
  __syncthreads();
  if (tid < 128) {
    float a = (rsum[0][tid] + rsum[1][tid]) + (rsum[2][tid] + rsum[3][tid]);
    float b = (rsq[0][tid] + rsq[1][tid]) + (rsq[2][tid] + rsq[3][tid]);
    atomicAdd(&sums[tid], a);
    atomicAdd(&sums[128 + tid], b);
  }
}

// ---------------- fused pair classifier (bf16 MFMA, BN2+ReLU fused into staging) ----------------
// 64 pairs/block, 4 waves. comb[64x256]bf16 (528B rows), z1[64x128]bf16 (272B),
// z2[64x64]bf16 (144B, aliases comb). Weights pre-packed frag-linear.

#define SM_Z1 33792
#define SM_TOT (33792 + 17408)

__global__ __launch_bounds__(256) void classifier_k(const f16* __restrict__ hA, const float* __restrict__ sums,
    const float* __restrict__ gamma, const float* __restrict__ beta,
    const int* __restrict__ pairs,
    const u16* __restrict__ Wc1F, const float* __restrict__ bc1,
    const u16* __restrict__ Wc2F, const float* __restrict__ bc2,
    const u16* __restrict__ Wc3F, const float* __restrict__ bc3,
    float* __restrict__ out) {
  __shared__ __align__(16) char smem[SM_TOT];
  __shared__ int nodes[128];
  __shared__ float scsh[256];
  int tid = threadIdx.x;
  int p0 = blockIdx.x * 64;
  if (tid < 128) {
    int gi = p0 * 2 + tid;
    nodes[tid] = (gi < NPAIRS * 2) ? pairs[gi] : 0;
    const float inv_n = 1.0f / (float)N_NODES;
    float mean = sums[tid] * inv_n;
    float var = sums[128 + tid] * inv_n - mean * mean;
    float sc = gamma[tid] * rsqrtf(var + 1e-5f);
    scsh[tid] = sc;
    scsh[128 + tid] = beta[tid] - mean * sc;
  }
  __syncthreads();
  int w = tid >> 6, lane = tid & 63;
  int li = lane & 15, kg = lane >> 4;

  // gather 128 node rows (fp16) -> BN2+ReLU -> bf16 comb (row-major, 528B pair stride)
  {
    unsigned int* cmb = (unsigned int*)smem;
    int c0 = lane * 2;
    float sc0 = scsh[c0], sh0 = scsh[128 + c0];
    float sc1 = scsh[c0 + 1], sh1 = scsh[128 + c0 + 1];
    union CV { u32 u; f16 h[2]; };
    for (int s = w * 32; s < w * 32 + 32; s++) {
      int nd = nodes[s];
      CV v; v.u = ((const u32*)hA)[(size_t)nd * 64 + lane];
      u32 b0 = f2bf(fmaxf((float)v.h[0] * sc0 + sh0, 0.f));
      u32 b1 = f2bf(fmaxf((float)v.h[1] * sc1 + sh1, 0.f));
      cmb[(s >> 1) * 132 + (s & 1) * 64 + lane] = b0 | (b1 << 16);
    }
  }
  __syncthreads();

  // phase 1: z1 = relu(comb @ Wc1 + bc1)   M=64 K=256 N=128; wave -> N-tiles {2w,2w+1}
  {
    f32x4 acc[4][2];
#pragma unroll
    for (int ntl = 0; ntl < 2; ntl++) {
      float b = bc1[(2 * w + ntl) * 16 + li];
#pragma unroll
      for (int mt = 0; mt < 4; mt++)
#pragma unroll
        for (int q = 0; q < 4; q++) acc[mt][ntl][q] = b;
    }
    for (int ks = 0; ks < 8; ks++) {
      short8v a[4];
#pragma unroll
      for (int mt = 0; mt < 4; mt++)
        a[mt] = *(const short8v*)(smem + (mt * 16 + li) * 528 + kg * 16 + ks * 64);
#pragma unroll
      for (int ntl = 0; ntl < 2; ntl++) {
        int nt = 2 * w + ntl;
        short8v b = *(const short8v*)(Wc1F + ((size_t)(nt * 8 + ks) * 64 + lane) * 8);
#pragma unroll
        for (int mt = 0; mt < 4; mt++)
          acc[mt][ntl] = __builtin_amdgcn_mfma_f32_16x16x32_bf16(a[mt], b, acc[mt][ntl], 0, 0, 0);
      }
    }
#pragma unroll
    for (int mt = 0; mt < 4; mt++)
#pragma unroll
      for (int ntl = 0; ntl < 2; ntl++)
#pragma unroll
        for (int r = 0; r < 4; r++) {
          int row = mt * 16 + kg * 4 + r;
          int col = (2 * w + ntl) * 16 + li;
          *(u16*)(smem + SM_Z1 + row * 272 + col * 2) = f2bf(fmaxf(acc[mt][ntl][r], 0.f));
        }
  }
  __syncthreads();

  // phase 2: z2 = relu(z1 @ Wc2 + bc2)   M=64 K=128 N=64; wave -> N-tile w
  {
    f32x4 acc[4];
    float b = bc2[w * 16 + li];
#pragma unroll
    for (int mt = 0; mt < 4; mt++)
#pragma unroll
      for (int q = 0; q < 4; q++) acc[mt][q] = b;
    for (int ks = 0; ks < 4; ks++) {
      short8v a[4];
#pragma unroll
      for (int mt = 0; mt < 4; mt++)
        a[mt] = *(const short8v*)(smem + SM_Z1 + (mt * 16 + li) * 272 + kg * 16 + ks * 64);
      short8v bf = *(const short8v*)(Wc2F + ((size_t)(w * 4 + ks) * 64 + lane) * 8);
#pragma unroll
      for (int mt = 0; mt < 4; mt++)
        acc[mt] = __builtin_amdgcn_mfma_f32_16x16x32_bf16(a[mt], bf, acc[mt], 0, 0, 0);
    }
#pragma unroll
    for (int mt = 0; mt < 4; mt++)
#pragma unroll
      for (int r = 0; r < 4; r++) {
        int row = mt * 16 + kg * 4 + r;
        int col = w * 16 + li;
        *(u16*)(smem + row * 144 + col * 2) = f2bf(fmaxf(acc[mt][r], 0.f));
      }
  }
  __syncthreads();

  // phase 3: out = z2 @ Wc3 + bc3   M=64 K=64 N=86 (padded 128); wave -> N-tiles {2w,2w+1}
  {
    f32x4 acc[4][2];
#pragma unroll
    for (int ntl = 0; ntl < 2; ntl++) {
      int col = (2 * w + ntl) * 16 + li;
      float b = (col < 86) ? bc3[col] : 0.f;
#pragma unroll
      for (int mt = 0; mt < 4; mt++)
#pragma unroll
        for (int q = 0; q < 4; q++) acc[mt][ntl][q] = b;
    }
    for (int ks = 0; ks < 2; ks++) {
      short8v a[4];
#pragma unroll
      for (int mt = 0; mt < 4; mt++)
        a[mt] = *(const short8v*)(smem + (mt * 16 + li) * 144 + kg * 16 + ks * 64);
#pragma unroll
      for (int ntl = 0; ntl < 2; ntl++) {
        int nt = 2 * w + ntl;
        short8v bf = *(const short8v*)(Wc3F + ((size_t)(nt * 2 + ks) * 64 + lane) * 8);
#pragma unroll
        for (int mt = 0; mt < 4; mt++)
          acc[mt][ntl] = __builtin_amdgcn_mfma_f32_16x16x32_bf16(a[mt], bf, acc[mt][ntl], 0, 0, 0);
      }
    }
#pragma unroll
    for (int mt = 0; mt < 4; mt++)
#pragma unroll
      for (int ntl = 0; ntl < 2; ntl++) {
        int col = (2 * w + ntl) * 16 + li;
        if (col < 86) {
#pragma unroll
          for (int r = 0; r < 4; r++) {
            int row = p0 + mt * 16 + kg * 4 + r;
            if (row < NPAIRS) out[(size_t)row * 86 + col] = acc[mt][ntl][r];
          }
        }
      }
  }
}

// ---------------- launch ----------------

extern "C" void kernel_launch(void* const* d_in, const int* in_sizes, int n_in,
                              void* d_out, int out_size, void* d_ws, size_t ws_size,
                              hipStream_t stream) {
  (void)in_sizes; (void)n_in; (void)out_size; (void)ws_size;
  const float* x   = (const float*)d_in[0];
  const int*   ei  = (const int*)d_in[1];
  const int* pairs = (const int*)d_in[2];
  const float* W1  = (const float*)d_in[3];
  const float* b1  = (const float*)d_in[4];
  const float* g1  = (const float*)d_in[5];
  const float* be1 = (const float*)d_in[6];
  const float* W2  = (const float*)d_in[7];
  const float* b2  = (const float*)d_in[8];
  const float* g2  = (const float*)d_in[9];
  const float* be2 = (const float*)d_in[10];
  const float* Wc1 = (const float*)d_in[11];
  const float* bc1 = (const float*)d_in[12];
  const float* Wc2 = (const float*)d_in[13];
  const float* bc2 = (const float*)d_in[14];
  const float* Wc3 = (const float*)d_in[15];
  const float* bc3 = (const float*)d_in[16];
  float* out = (float*)d_out;

  size_t off = 0;
  auto alloc = [&](size_t bytes) -> char* {
    char* p = (char*)d_ws + off;
    off += (bytes + 255) & ~(size_t)255;
    return p;
  };
  int* deg      = (int*)alloc(N_NODES * 4);
  float* sums1  = (float*)alloc(256 * 4);
  float* sums2  = (float*)alloc(256 * 4);
  size_t zero_span = off;
  int* offs     = (int*)alloc((N_NODES + 1) * 4);
  int* rank     = (int*)alloc(N_EDGES * 4);
  u32* csrp     = (u32*)alloc(N_EDGES * 4);
  float* dinv   = (float*)alloc(N_NODES * 4);
  f16* W1F      = (f16*)alloc(2048 * 8 * 2);
  f16* W2F      = (f16*)alloc(2048 * 8 * 2);
  u16* Wc1F     = (u16*)alloc(4096 * 8 * 2);
  u16* Wc2F     = (u16*)alloc(1024 * 8 * 2);
  u16* Wc3F     = (u16*)alloc(1024 * 8 * 2);
  f16* th       = (f16*)alloc((size_t)N_NODES * 128 * 2);
  f16* hA       = (f16*)alloc((size_t)N_NODES * 128 * 2);

  hipMemsetAsync(d_ws, 0, zero_span, stream);
  wpack_k<<<40, 256, 0, stream>>>(W1, W2, Wc1, Wc2, Wc3, W1F, W2F, Wc1F, Wc2F, Wc3F);

  // edge-rank count overlapped with gemm1 (t1 = x @ W1)
  fused1_k<<<N_EDGES / 256 + (N_NODES + 63) / 64, 256, 0, stream>>>(ei, deg, rank, x, W1F, th, N_NODES);
  scan_k<<<1, 1024, 0, stream>>>(deg, offs, dinv, N_NODES);
  fill_k<<<N_EDGES / 256, 256, 0, stream>>>(ei, offs, rank, dinv, csrp, N_EDGES);

  // layer 1: agg; stats1
  agg_h_k<<<(N_NODES + 3) / 4, 256, 0, stream>>>(th, dinv, offs, csrp, b1, hA, N_NODES);
  bn_stats_h_k<<<256, 256, 0, stream>>>(hA, sums1, N_NODES);

  // layer 2: t2 = bnrelu(h1) @ W2; agg; stats2
  gemm2_k<<<(N_NODES + 63) / 64, 256, 0, stream>>>(hA, sums1, g1, be1, W2F, th, N_NODES);
  agg_h_k<<<(N_NODES + 3) / 4, 256, 0, stream>>>(th, dinv, offs, csrp, b2, hA, N_NODES);
  bn_stats_h_k<<<256, 256, 0, stream>>>(hA, sums2, N_NODES);

  // classifier (BN2+ReLU fused into staging)
  classifier_k<<<(NPAIRS + 63) / 64, 256, 0, stream>>>(hA, sums2, g2, be2, pairs,
                                                       Wc1F, bc1, Wc2F, bc2, Wc3F, bc3, out);
}